// Round 2
// baseline (2047.904 us; speedup 1.0000x reference)
//
#include <hip/hip_runtime.h>
#include <hip/hip_bf16.h>
#include <stdint.h>

// ---------------------------------------------------------------------------
// Problem geometry
//   x (4,400,128) -> conv1d(200->512,k3,p1,relu) -> conv1d(512->128,k3,p1,relu) = h
//   x4 = sigmoid(0.01*conv1d(h, w3(3,128,1))) -> outputs xc(ch2), xb_start(ch0), xb_end(ch1)
//   cm = einsum('bct,tm->bcm', h, mask) ; conv3d(w3d, stride 32) + b3d, relu
//     == relu(b3d[o] + sum_{s,t} mask[t,s,i,j] * H2[b,o,s,t]),
//        H2[b,o,s,t] = sum_c w3d[o,c,s] * h[b,c,t]      (mask: <=6 taps per (s,i,j))
//   then 1x1(512->128,relu), 3x3(128->64,relu), 3x3(64->64,relu), 1x1(64->4,sigmoid)
//   outputs (float32): xc,xb_start,xb_end (3*512) | iou (4,2,128,128) | prop_start | prop_end
// ---------------------------------------------------------------------------

typedef unsigned int uint32;

__device__ __forceinline__ float bf2f(ushort u) {
    return __uint_as_float(((uint32)u) << 16);
}
__device__ __forceinline__ ushort f2bf(float f) {
    uint32 x = __float_as_uint(f);
    uint32 r = (x + 0x7FFFu + ((x >> 16) & 1u)) >> 16;
    return (ushort)r;
}
__device__ __forceinline__ float sigmoidf(float x) {
    return 1.0f / (1.0f + __expf(-x));
}

// ---------------------------------------------------------------------------
// conv1d (k=3, pad=1, relu). Block: 16 out-channels x 128 t. Grid (COUT/16, B).
// ---------------------------------------------------------------------------
__global__ __launch_bounds__(256) void k_conv1d_relu(
    const float* __restrict__ in, const float* __restrict__ w,
    const float* __restrict__ bias, float* __restrict__ out,
    int CIN, int in_batch_stride, int COUT)
{
    __shared__ float lx[64 * 132];   // [c][0..127 data, 128 = zero pad]
    int b  = blockIdx.y;
    int o  = blockIdx.x * 16 + (threadIdx.x >> 4);
    int tg = threadIdx.x & 15;
    int t0 = tg * 8;

    float acc[8];
#pragma unroll
    for (int k = 0; k < 8; ++k) acc[k] = 0.0f;

    for (int c0 = 0; c0 < CIN; c0 += 64) {
        int nc = CIN - c0; if (nc > 64) nc = 64;
        __syncthreads();
        for (int n = threadIdx.x; n < nc * 32; n += 256) {
            int cl = n >> 5, q = n & 31;
            float4 v = *(const float4*)(in + ((size_t)(b * in_batch_stride + c0 + cl)) * 128 + q * 4);
            *(float4*)(&lx[cl * 132 + q * 4]) = v;
        }
        for (int cl = threadIdx.x; cl < nc; cl += 256) lx[cl * 132 + 128] = 0.0f;
        __syncthreads();

        for (int cl = 0; cl < nc; ++cl) {
            int c = c0 + cl;
            const float* wp = w + ((size_t)o * CIN + c) * 3;
            float w0 = wp[0], w1 = wp[1], w2 = wp[2];
            const float* row = &lx[cl * 132];
            float xv[10];
            if (t0 == 0) {
                xv[0] = 0.0f;
#pragma unroll
                for (int k = 1; k < 10; ++k) xv[k] = row[k - 1];
            } else {
#pragma unroll
                for (int k = 0; k < 10; ++k) xv[k] = row[t0 - 1 + k];
            }
#pragma unroll
            for (int k = 0; k < 8; ++k)
                acc[k] += w0 * xv[k] + w1 * xv[k + 1] + w2 * xv[k + 2];
        }
    }
    float bo = bias[o];
#pragma unroll
    for (int k = 0; k < 8; ++k) {
        float v = acc[k] + bo;
        out[((size_t)(b * COUT + o)) * 128 + t0 + k] = v > 0.0f ? v : 0.0f;
    }
}

// ---------------------------------------------------------------------------
// x4 head -> d_out[0:1536] floats: (xc=ch2 | xb_start=ch0 | xb_end=ch1)
// ---------------------------------------------------------------------------
__global__ void k_x4(const float* __restrict__ h, const float* __restrict__ w3,
                     const float* __restrict__ b3, float* __restrict__ outp)
{
    int tid = threadIdx.x;
    int b = tid >> 7, t = tid & 127;
    float a0 = 0.f, a1 = 0.f, a2 = 0.f;
    for (int c = 0; c < 128; ++c) {
        float hv = h[((size_t)(b * 128 + c)) * 128 + t];
        a0 += w3[c] * hv;
        a1 += w3[128 + c] * hv;
        a2 += w3[256 + c] * hv;
    }
    float s0 = sigmoidf(0.01f * (a0 + b3[0]));
    float s1 = sigmoidf(0.01f * (a1 + b3[1]));
    float s2 = sigmoidf(0.01f * (a2 + b3[2]));
    int bt = b * 128 + t;
    outp[bt]        = s2;   // xc
    outp[512 + bt]  = s0;   // xb_start
    outp[1024 + bt] = s1;   // xb_end
}

// ---------------------------------------------------------------------------
// H2t[(s*128+t)*2048 + b*512+o] = bf16( sum_c w3d[o,c,s]*h[b,c,t] )
// ---------------------------------------------------------------------------
__global__ __launch_bounds__(256) void k_h2(
    const float* __restrict__ h, const float* __restrict__ w3d,
    ushort* __restrict__ h2t)
{
    __shared__ float lw[64 * 129];     // [o][c]
    __shared__ float lhs[32 * 132];    // [c_local][t] ; reused as ushort out stage
    int ot = blockIdx.x, s = blockIdx.y, b = blockIdx.z;
    int o0 = ot * 64;

    for (int n = threadIdx.x; n < 8192; n += 256) {
        int o = n >> 7, c = n & 127;
        lw[o * 129 + c] = w3d[(size_t)(o0 + o) * 4096 + c * 32 + s];
    }

    int og = threadIdx.x >> 4, tg = threadIdx.x & 15;
    int o0t = og * 4, t0 = tg * 8;
    float acc[4][8];
#pragma unroll
    for (int oo = 0; oo < 4; ++oo)
#pragma unroll
        for (int k = 0; k < 8; ++k) acc[oo][k] = 0.0f;

    for (int c0 = 0; c0 < 128; c0 += 32) {
        __syncthreads();
        for (int n = threadIdx.x; n < 1024; n += 256) {
            int cl = n >> 5, q = n & 31;
            *(float4*)(&lhs[cl * 132 + q * 4]) =
                *(const float4*)(h + ((size_t)(b * 128 + c0 + cl)) * 128 + q * 4);
        }
        __syncthreads();
        for (int cl = 0; cl < 32; ++cl) {
            float hv[8];
#pragma unroll
            for (int k = 0; k < 8; ++k) hv[k] = lhs[cl * 132 + t0 + k];
#pragma unroll
            for (int oo = 0; oo < 4; ++oo) {
                float wv = lw[(o0t + oo) * 129 + c0 + cl];
#pragma unroll
                for (int k = 0; k < 8; ++k) acc[oo][k] += wv * hv[k];
            }
        }
    }
    __syncthreads();
    ushort* lout = (ushort*)lhs;       // [t*64 + o]
#pragma unroll
    for (int oo = 0; oo < 4; ++oo)
#pragma unroll
        for (int k = 0; k < 8; ++k)
            lout[(t0 + k) * 64 + o0t + oo] = f2bf(acc[oo][k]);
    __syncthreads();
    for (int n = threadIdx.x; n < 8192; n += 256) {
        int t = n >> 6, o = n & 63;
        h2t[(size_t)(s * 128 + t) * 2048 + b * 512 + o0 + o] = lout[n];
    }
}

// ---------------------------------------------------------------------------
// E1: per mask column m=(s,i,j), collect nonzero (t,w) taps (<=6 exist, cap 8).
// ---------------------------------------------------------------------------
__global__ __launch_bounds__(256) void k_e1(
    const float* __restrict__ mask, uint32* __restrict__ ecnt,
    uint8_t* __restrict__ et, float* __restrict__ ew)
{
    uint32 m = blockIdx.x * 256 + threadIdx.x;
    int cnt = 0;
    for (int t = 0; t < 128; ++t) {
        float w = mask[(size_t)t * 524288 + m];
        if (w != 0.0f) {
            if (cnt < 8) {
                et[(size_t)m * 8 + cnt] = (uint8_t)t;
                ew[(size_t)m * 8 + cnt] = w;
            }
            cnt++;
        }
    }
    ecnt[m] = (uint32)(cnt < 8 ? cnt : 8);
}

// ---------------------------------------------------------------------------
// E2: merge per (i,j): taps over all 32 s -> packed {w_bits, st} records (<=192).
// ---------------------------------------------------------------------------
__global__ void k_e2(const uint32* __restrict__ ecnt, const uint8_t* __restrict__ et,
                     const float* __restrict__ ew, uint32* __restrict__ cntij,
                     int2* __restrict__ taps)
{
    int lane = threadIdx.x & 31;
    int col = blockIdx.x * 2 + (threadIdx.x >> 5);
    uint32 m = (uint32)lane * 16384u + (uint32)col;
    int c = (int)ecnt[m];
    int v = c;
    for (int d = 1; d < 32; d <<= 1) {
        int t = __shfl_up(v, d, 32);
        if (lane >= d) v += t;
    }
    int off = v - c;
    if (lane == 31) cntij[col] = (uint32)v;
    for (int k = 0; k < c; ++k) {
        int2 r;
        r.x = __float_as_int(ew[(size_t)m * 8 + k]);
        r.y = lane * 128 + (int)et[(size_t)m * 8 + k];
        taps[(size_t)col * 192 + off + k] = r;
    }
}

// ---------------------------------------------------------------------------
// k_bm: cm[bo, ij] = relu(b3d[o] + sum_taps w * H2t[st, bo])   (bf16 out)
// ---------------------------------------------------------------------------
__global__ __launch_bounds__(256) void k_bm(
    const ushort* __restrict__ h2t, const int2* __restrict__ taps,
    const uint32* __restrict__ cntij, const float* __restrict__ b3d,
    ushort* __restrict__ cm)
{
    __shared__ int2 tl[192];
    __shared__ ushort lout[64 * 266];   // [jj][bo_local]
    int jt = blockIdx.x, i = blockIdx.y, boT = blockIdx.z;
    int bo = boT * 256 + threadIdx.x;
    float bias = b3d[bo & 511];
    int ij0 = i * 128 + jt * 64;

    for (int jj = 0; jj < 64; ++jj) {
        int ij = ij0 + jj;
        int cnt = (int)cntij[ij];
        __syncthreads();
        if ((int)threadIdx.x < cnt) tl[threadIdx.x] = taps[(size_t)ij * 192 + threadIdx.x];
        __syncthreads();
        float a = 0.0f;
#pragma unroll 4
        for (int k = 0; k < cnt; ++k) {
            int2 r = tl[k];
            a += __int_as_float(r.x) * bf2f(h2t[(size_t)((uint32)r.y) * 2048u + bo]);
        }
        float v = a + bias;
        v = v > 0.0f ? v : 0.0f;
        lout[jj * 266 + threadIdx.x] = f2bf(v);
    }
    __syncthreads();
    int wv = threadIdx.x >> 6, lane = threadIdx.x & 63;
    for (int rr = 0; rr < 64; rr += 2) {
        int r = wv * 64 + rr;
        uint32 pr = *(const uint32*)&lout[lane * 266 + r];
        cm[(size_t)(boT * 256 + r) * 16384 + ij0 + lane]     = (ushort)(pr & 0xffffu);
        cm[(size_t)(boT * 256 + r + 1) * 16384 + ij0 + lane] = (ushort)(pr >> 16);
    }
}

// ---------------------------------------------------------------------------
// conv-a: 1x1, 512 -> 128, relu.
// ---------------------------------------------------------------------------
__global__ __launch_bounds__(256) void k_conva(
    const ushort* __restrict__ cm, const float* __restrict__ wa,
    const float* __restrict__ ba, float* __restrict__ p1)
{
    __shared__ float lx[32 * 132];   // [oo][j]
    __shared__ float lwv[32 * 132];  // [oo][c]
    int i = blockIdx.x, b = blockIdx.y;
    int cg = threadIdx.x >> 4, jg = threadIdx.x & 15;
    int c0 = cg * 8, j0 = jg * 8;
    float acc[8][8];
#pragma unroll
    for (int cc = 0; cc < 8; ++cc)
#pragma unroll
        for (int k = 0; k < 8; ++k) acc[cc][k] = 0.0f;

    for (int o0 = 0; o0 < 512; o0 += 32) {
        __syncthreads();
        for (int n = threadIdx.x; n < 512; n += 256) {
            int oo = n >> 4, q = n & 15;
            uint4 v = *(const uint4*)(cm + (size_t)(b * 512 + o0 + oo) * 16384 + i * 128 + q * 8);
            float* dst = &lx[oo * 132 + q * 8];
            dst[0] = bf2f((ushort)(v.x & 0xffffu)); dst[1] = bf2f((ushort)(v.x >> 16));
            dst[2] = bf2f((ushort)(v.y & 0xffffu)); dst[3] = bf2f((ushort)(v.y >> 16));
            dst[4] = bf2f((ushort)(v.z & 0xffffu)); dst[5] = bf2f((ushort)(v.z >> 16));
            dst[6] = bf2f((ushort)(v.w & 0xffffu)); dst[7] = bf2f((ushort)(v.w >> 16));
        }
        for (int n = threadIdx.x; n < 4096; n += 256) {
            int oo = n & 31, c = n >> 5;
            lwv[oo * 132 + c] = wa[(size_t)c * 512 + o0 + oo];
        }
        __syncthreads();
        for (int oo = 0; oo < 32; ++oo) {
            float xv[8], wvv[8];
#pragma unroll
            for (int k = 0; k < 8; ++k) xv[k] = lx[oo * 132 + j0 + k];
#pragma unroll
            for (int k = 0; k < 8; ++k) wvv[k] = lwv[oo * 132 + c0 + k];
#pragma unroll
            for (int cc = 0; cc < 8; ++cc)
#pragma unroll
                for (int k = 0; k < 8; ++k) acc[cc][k] += wvv[cc] * xv[k];
        }
    }
#pragma unroll
    for (int cc = 0; cc < 8; ++cc) {
        float bb = ba[c0 + cc];
#pragma unroll
        for (int k = 0; k < 8; ++k) {
            float v = acc[cc][k] + bb;
            v = v > 0.0f ? v : 0.0f;
            p1[((size_t)(b * 128 + c0 + cc)) * 16384 + i * 128 + j0 + k] = v;
        }
    }
}

// ---------------------------------------------------------------------------
// 3x3 conv, CIN -> 64, pad 1, relu.
// ---------------------------------------------------------------------------
template <int CIN>
__global__ __launch_bounds__(256) void k_conv3x3(
    const float* __restrict__ in, const float* __restrict__ w,
    const float* __restrict__ bias, float* __restrict__ out)
{
    __shared__ float lx[3 * 132];   // 3 input rows, padded cols 0..129
    __shared__ float lws[576];      // 64 c x 9
    int i = blockIdx.x, b = blockIdx.y;
    int cg = threadIdx.x >> 4, jg = threadIdx.x & 15;
    int c0 = cg * 4, j0 = jg * 8;
    float acc[4][8];
#pragma unroll
    for (int cc = 0; cc < 4; ++cc)
#pragma unroll
        for (int k = 0; k < 8; ++k) acc[cc][k] = 0.0f;

    for (int o = 0; o < CIN; ++o) {
        __syncthreads();
        for (int n = threadIdx.x; n < 390; n += 256) {
            int r = n / 130, col = n % 130;
            int ii = i + r - 1, jj = col - 1;
            float v = 0.0f;
            if (ii >= 0 && ii < 128 && jj >= 0 && jj < 128)
                v = in[((size_t)(b * CIN + o) * 128 + ii) * 128 + jj];
            lx[r * 132 + col] = v;
        }
        for (int n = threadIdx.x; n < 576; n += 256)
            lws[n] = w[((size_t)(n / 9) * CIN + o) * 9 + (n % 9)];
        __syncthreads();

        float x0[10], x1[10], x2[10];
#pragma unroll
        for (int k = 0; k < 10; ++k) {
            x0[k] = lx[0 * 132 + j0 + k];
            x1[k] = lx[1 * 132 + j0 + k];
            x2[k] = lx[2 * 132 + j0 + k];
        }
#pragma unroll
        for (int cc = 0; cc < 4; ++cc) {
            const float* wp = &lws[(c0 + cc) * 9];
            float w00 = wp[0], w01 = wp[1], w02 = wp[2];
            float w10 = wp[3], w11 = wp[4], w12 = wp[5];
            float w20 = wp[6], w21 = wp[7], w22 = wp[8];
#pragma unroll
            for (int k = 0; k < 8; ++k) {
                acc[cc][k] += w00 * x0[k] + w01 * x0[k + 1] + w02 * x0[k + 2]
                            + w10 * x1[k] + w11 * x1[k + 1] + w12 * x1[k + 2]
                            + w20 * x2[k] + w21 * x2[k + 1] + w22 * x2[k + 2];
            }
        }
    }
#pragma unroll
    for (int cc = 0; cc < 4; ++cc) {
        float bb = bias[c0 + cc];
#pragma unroll
        for (int k = 0; k < 8; ++k) {
            float v = acc[cc][k] + bb;
            v = v > 0.0f ? v : 0.0f;
            out[((size_t)(b * 64 + c0 + cc) * 128 + i) * 128 + j0 + k] = v;
        }
    }
}

// ---------------------------------------------------------------------------
// conv-d: 1x1, 64 -> 4, sigmoid, scatter to d_out floats
// (iou = ch2,3 at 1536; prop_start = ch0 at 132608; prop_end = ch1 at 198144)
// ---------------------------------------------------------------------------
__global__ __launch_bounds__(256) void k_convd(
    const float* __restrict__ p3, const float* __restrict__ wd,
    const float* __restrict__ bd, float* __restrict__ outp)
{
    __shared__ float lw[256];
    int b = blockIdx.y;
    int ij = blockIdx.x * 256 + threadIdx.x;
    lw[threadIdx.x] = wd[threadIdx.x];
    __syncthreads();
    float a0 = bd[0], a1 = bd[1], a2 = bd[2], a3 = bd[3];
    for (int c = 0; c < 64; ++c) {
        float v = p3[((size_t)(b * 64 + c)) * 16384 + ij];
        a0 += lw[c] * v;
        a1 += lw[64 + c] * v;
        a2 += lw[128 + c] * v;
        a3 += lw[192 + c] * v;
    }
    outp[1536 + (size_t)(b * 2 + 0) * 16384 + ij] = sigmoidf(a2);  // iou ch0
    outp[1536 + (size_t)(b * 2 + 1) * 16384 + ij] = sigmoidf(a3);  // iou ch1
    outp[132608 + (size_t)b * 16384 + ij] = sigmoidf(a0);          // prop_start
    outp[198144 + (size_t)b * 16384 + ij] = sigmoidf(a1);          // prop_end
}

// ---------------------------------------------------------------------------
extern "C" void kernel_launch(void* const* d_in, const int* in_sizes, int n_in,
                              void* d_out, int out_size, void* d_ws, size_t ws_size,
                              hipStream_t stream)
{
    const float* x   = (const float*)d_in[0];
    const float* w1  = (const float*)d_in[1];
    const float* b1  = (const float*)d_in[2];
    const float* w2  = (const float*)d_in[3];
    const float* b2  = (const float*)d_in[4];
    const float* w3  = (const float*)d_in[5];
    const float* b3  = (const float*)d_in[6];
    const float* w3d = (const float*)d_in[7];
    const float* b3d = (const float*)d_in[8];
    const float* wa  = (const float*)d_in[9];
    const float* ba  = (const float*)d_in[10];
    const float* wb  = (const float*)d_in[11];
    const float* bb  = (const float*)d_in[12];
    const float* wc  = (const float*)d_in[13];
    const float* bc  = (const float*)d_in[14];
    const float* wd  = (const float*)d_in[15];
    const float* bd  = (const float*)d_in[16];
    const float* sm  = (const float*)d_in[17];
    float* outp = (float*)d_out;
    char* ws = (char*)d_ws;

    // workspace layout (with aliasing; peak ~127.3 MB)
    float*  h1    = (float*)(ws + 0);              //  1,048,576 B
    float*  h     = (float*)(ws + 1048576);        //    262,144 B
    ushort* h2t   = (ushort*)(ws + 1310720);       // 16,777,216 B
    uint32* ecnt  = (uint32*)(ws + 18087936);      //  2,097,152 B
    uint8_t* et   = (uint8_t*)(ws + 20185088);     //  4,194,304 B
    float*  ewf   = (float*)(ws + 24379392);       // 16,777,216 B
    uint32* cntij = (uint32*)(ws + 41156608);      //     65,536 B
    int2*   taps  = (int2*)(ws + 41222144);        // 25,165,824 B
    ushort* cm    = (ushort*)(ws + 66387968);      // 67,108,864 B  -> ends 133,496,832
    float*  p1    = (float*)(ws + 1310720);        // 33,554,432 B (aliases h2t+e-bufs; dead then)
    float*  p2    = (float*)(ws + 41222144);       // 16,777,216 B (aliases taps; dead then)
    float*  p3    = (float*)(ws + 66387968);       // 16,777,216 B (aliases cm; dead then)

    dim3 blk(256);
    k_conv1d_relu<<<dim3(32, 4), blk, 0, stream>>>(x, w1, b1, h1, 200, 400, 512);
    k_conv1d_relu<<<dim3(8, 4), blk, 0, stream>>>(h1, w2, b2, h, 512, 512, 128);
    k_x4<<<1, 512, 0, stream>>>(h, w3, b3, outp);
    k_h2<<<dim3(8, 32, 4), blk, 0, stream>>>(h, w3d, h2t);
    k_e1<<<2048, blk, 0, stream>>>(sm, ecnt, et, ewf);
    k_e2<<<8192, 64, 0, stream>>>(ecnt, et, ewf, cntij, taps);
    k_bm<<<dim3(2, 128, 8), blk, 0, stream>>>(h2t, taps, cntij, b3d, cm);
    k_conva<<<dim3(128, 4), blk, 0, stream>>>(cm, wa, ba, p1);
    k_conv3x3<128><<<dim3(128, 4), blk, 0, stream>>>(p1, wb, bb, p2);
    k_conv3x3<64><<<dim3(128, 4), blk, 0, stream>>>(p2, wc, bc, p3);
    k_convd<<<dim3(64, 4), blk, 0, stream>>>(p3, wd, bd, outp);
}

// Round 4
// 1334.228 us; speedup vs baseline: 1.5349x; 1.5349x over previous
//
#include <hip/hip_runtime.h>
#include <hip/hip_bf16.h>
#include <stdint.h>

// ---------------------------------------------------------------------------
// Problem geometry
//   x (4,400,128) -> conv1d(200->512,k3,p1,relu) -> conv1d(512->128,k3,p1,relu) = h
//   x4 = sigmoid(0.01*conv1d(h, w3(3,128,1))) -> outputs xc(ch2), xb_start(ch0), xb_end(ch1)
//   cm = einsum('bct,tm->bcm', h, mask) ; conv3d(w3d, stride 32) + b3d, relu
//     == relu(b3d[o] + sum_{s,t} mask[t,s,i,j] * H2[b,o,s,t]),
//        H2[b,o,s,t] = sum_c w3d[o,c,s] * h[b,c,t]      (mask: <=6 taps per (s,i,j))
//   then 1x1(512->128,relu), 3x3(128->64,relu), 3x3(64->64,relu), 1x1(64->4,sigmoid)
//   outputs (float32): xc,xb_start,xb_end (3*512) | iou (4,2,128,128) | prop_start | prop_end
// ---------------------------------------------------------------------------

typedef unsigned int uint32;

__device__ __forceinline__ float bf2f(ushort u) {
    return __uint_as_float(((uint32)u) << 16);
}
__device__ __forceinline__ ushort f2bf(float f) {
    uint32 x = __float_as_uint(f);
    uint32 r = (x + 0x7FFFu + ((x >> 16) & 1u)) >> 16;
    return (ushort)r;
}
__device__ __forceinline__ float sigmoidf(float x) {
    return 1.0f / (1.0f + __expf(-x));
}

// ---------------------------------------------------------------------------
// conv1d (k=3, pad=1, relu). Block: 16 out-channels x 128 t. Grid (COUT/16, B).
// ---------------------------------------------------------------------------
__global__ __launch_bounds__(256) void k_conv1d_relu(
    const float* __restrict__ in, const float* __restrict__ w,
    const float* __restrict__ bias, float* __restrict__ out,
    int CIN, int in_batch_stride, int COUT)
{
    __shared__ float lx[64 * 132];   // [c][0..127 data, 128 = zero pad]
    int b  = blockIdx.y;
    int o  = blockIdx.x * 16 + (threadIdx.x >> 4);
    int tg = threadIdx.x & 15;
    int t0 = tg * 8;

    float acc[8];
#pragma unroll
    for (int k = 0; k < 8; ++k) acc[k] = 0.0f;

    for (int c0 = 0; c0 < CIN; c0 += 64) {
        int nc = CIN - c0; if (nc > 64) nc = 64;
        __syncthreads();
        for (int n = threadIdx.x; n < nc * 32; n += 256) {
            int cl = n >> 5, q = n & 31;
            float4 v = *(const float4*)(in + ((size_t)(b * in_batch_stride + c0 + cl)) * 128 + q * 4);
            *(float4*)(&lx[cl * 132 + q * 4]) = v;
        }
        for (int cl = threadIdx.x; cl < nc; cl += 256) lx[cl * 132 + 128] = 0.0f;
        __syncthreads();

        for (int cl = 0; cl < nc; ++cl) {
            int c = c0 + cl;
            const float* wp = w + ((size_t)o * CIN + c) * 3;
            float w0 = wp[0], w1 = wp[1], w2 = wp[2];
            const float* row = &lx[cl * 132];
            float xv[10];
            if (t0 == 0) {
                xv[0] = 0.0f;
#pragma unroll
                for (int k = 1; k < 10; ++k) xv[k] = row[k - 1];
            } else {
#pragma unroll
                for (int k = 0; k < 10; ++k) xv[k] = row[t0 - 1 + k];
            }
#pragma unroll
            for (int k = 0; k < 8; ++k)
                acc[k] += w0 * xv[k] + w1 * xv[k + 1] + w2 * xv[k + 2];
        }
    }
    float bo = bias[o];
#pragma unroll
    for (int k = 0; k < 8; ++k) {
        float v = acc[k] + bo;
        out[((size_t)(b * COUT + o)) * 128 + t0 + k] = v > 0.0f ? v : 0.0f;
    }
}

// ---------------------------------------------------------------------------
// x4 head -> d_out[0:1536] floats: (xc=ch2 | xb_start=ch0 | xb_end=ch1)
// ---------------------------------------------------------------------------
__global__ void k_x4(const float* __restrict__ h, const float* __restrict__ w3,
                     const float* __restrict__ b3, float* __restrict__ outp)
{
    int tid = threadIdx.x;
    int b = tid >> 7, t = tid & 127;
    float a0 = 0.f, a1 = 0.f, a2 = 0.f;
    for (int c = 0; c < 128; ++c) {
        float hv = h[((size_t)(b * 128 + c)) * 128 + t];
        a0 += w3[c] * hv;
        a1 += w3[128 + c] * hv;
        a2 += w3[256 + c] * hv;
    }
    float s0 = sigmoidf(0.01f * (a0 + b3[0]));
    float s1 = sigmoidf(0.01f * (a1 + b3[1]));
    float s2 = sigmoidf(0.01f * (a2 + b3[2]));
    int bt = b * 128 + t;
    outp[bt]        = s2;   // xc
    outp[512 + bt]  = s0;   // xb_start
    outp[1024 + bt] = s1;   // xb_end
}

// ---------------------------------------------------------------------------
// H2t[(s*128+t)*2048 + b*512+o] = bf16( sum_c w3d[o,c,s]*h[b,c,t] )
// ---------------------------------------------------------------------------
__global__ __launch_bounds__(256) void k_h2(
    const float* __restrict__ h, const float* __restrict__ w3d,
    ushort* __restrict__ h2t)
{
    __shared__ float lw[64 * 129];     // [o][c]
    __shared__ float lhs[32 * 132];    // [c_local][t] ; reused as ushort out stage
    int ot = blockIdx.x, s = blockIdx.y, b = blockIdx.z;
    int o0 = ot * 64;

    for (int n = threadIdx.x; n < 8192; n += 256) {
        int o = n >> 7, c = n & 127;
        lw[o * 129 + c] = w3d[(size_t)(o0 + o) * 4096 + c * 32 + s];
    }

    int og = threadIdx.x >> 4, tg = threadIdx.x & 15;
    int o0t = og * 4, t0 = tg * 8;
    float acc[4][8];
#pragma unroll
    for (int oo = 0; oo < 4; ++oo)
#pragma unroll
        for (int k = 0; k < 8; ++k) acc[oo][k] = 0.0f;

    for (int c0 = 0; c0 < 128; c0 += 32) {
        __syncthreads();
        for (int n = threadIdx.x; n < 1024; n += 256) {
            int cl = n >> 5, q = n & 31;
            *(float4*)(&lhs[cl * 132 + q * 4]) =
                *(const float4*)(h + ((size_t)(b * 128 + c0 + cl)) * 128 + q * 4);
        }
        __syncthreads();
        for (int cl = 0; cl < 32; ++cl) {
            float hv[8];
#pragma unroll
            for (int k = 0; k < 8; ++k) hv[k] = lhs[cl * 132 + t0 + k];
#pragma unroll
            for (int oo = 0; oo < 4; ++oo) {
                float wv = lw[(o0t + oo) * 129 + c0 + cl];
#pragma unroll
                for (int k = 0; k < 8; ++k) acc[oo][k] += wv * hv[k];
            }
        }
    }
    __syncthreads();
    ushort* lout = (ushort*)lhs;       // [t*64 + o]
#pragma unroll
    for (int oo = 0; oo < 4; ++oo)
#pragma unroll
        for (int k = 0; k < 8; ++k)
            lout[(t0 + k) * 64 + o0t + oo] = f2bf(acc[oo][k]);
    __syncthreads();
    for (int n = threadIdx.x; n < 8192; n += 256) {
        int t = n >> 6, o = n & 63;
        h2t[(size_t)(s * 128 + t) * 2048 + b * 512 + o0 + o] = lout[n];
    }
}

// ---------------------------------------------------------------------------
// E1: per mask column m=(s,i,j), collect nonzero (t,w) taps (<=6 exist, cap 8).
// ---------------------------------------------------------------------------
__global__ __launch_bounds__(256) void k_e1(
    const float* __restrict__ mask, uint32* __restrict__ ecnt,
    uint8_t* __restrict__ et, float* __restrict__ ew)
{
    uint32 m = blockIdx.x * 256 + threadIdx.x;
    int cnt = 0;
    for (int t = 0; t < 128; ++t) {
        float w = mask[(size_t)t * 524288 + m];
        if (w != 0.0f) {
            if (cnt < 8) {
                et[(size_t)m * 8 + cnt] = (uint8_t)t;
                ew[(size_t)m * 8 + cnt] = w;
            }
            cnt++;
        }
    }
    ecnt[m] = (uint32)(cnt < 8 ? cnt : 8);
}

// ---------------------------------------------------------------------------
// E2: merge per (i,j): taps over all 32 s -> packed {w_bits, byte_off} (<=192).
// byte_off = st * 4096 (h2t row pitch in bytes) so k_bm's inner loop is lean.
// ---------------------------------------------------------------------------
__global__ void k_e2(const uint32* __restrict__ ecnt, const uint8_t* __restrict__ et,
                     const float* __restrict__ ew, uint32* __restrict__ cntij,
                     int2* __restrict__ taps)
{
    int lane = threadIdx.x & 31;
    int col = blockIdx.x * 2 + (threadIdx.x >> 5);
    uint32 m = (uint32)lane * 16384u + (uint32)col;
    int c = (int)ecnt[m];
    int v = c;
    for (int d = 1; d < 32; d <<= 1) {
        int t = __shfl_up(v, d, 32);
        if (lane >= d) v += t;
    }
    int off = v - c;
    if (lane == 31) cntij[col] = (uint32)v;
    for (int k = 0; k < c; ++k) {
        int2 r;
        r.x = __float_as_int(ew[(size_t)m * 8 + k]);
        r.y = ((lane << 7) + (int)et[(size_t)m * 8 + k]) << 12;   // st * 4096 bytes
        taps[(size_t)col * 192 + off + k] = r;
    }
}

// ---------------------------------------------------------------------------
// k_bm: cm[bo, ij] = relu(b3d[o] + sum_taps w * H2t[st, bo])   (bf16 out)
// Grid (x=boT 8, y=i 128): x fastest -> round-robin pins each bo-slice (2 MB of
// h2t) to one XCD's L2. One block does the whole i-row (128 cols); taps staged
// 8 cols per barrier; nontemporal cm stores keep the write stream out of L2.
// ---------------------------------------------------------------------------
__global__ __launch_bounds__(256) void k_bm(
    const ushort* __restrict__ h2t, const int2* __restrict__ taps,
    const uint32* __restrict__ cntij, const float* __restrict__ b3d,
    ushort* __restrict__ cm)
{
    __shared__ int2 tl[8 * 192];        // 12,288 B
    __shared__ ushort lout[128 * 257];  // 65,792 B ; [col][bo_local], stride 257
    int boT = blockIdx.x, i = blockIdx.y;
    int tid = threadIdx.x;
    int bo = boT * 256 + tid;
    int bo_byte = bo * 2;
    float bias = b3d[bo & 511];
    const char* h2b = (const char*)h2t;

    for (int jc = 0; jc < 16; ++jc) {
        int j0 = jc * 8;
        int ij0 = i * 128 + j0;
        int cnts[8];
#pragma unroll
        for (int c = 0; c < 8; ++c) cnts[c] = (int)cntij[ij0 + c];
        __syncthreads();   // previous chunk's readers done before tl overwrite
        for (int n = tid; n < 1536; n += 256) {
            int c = n / 192, k = n - c * 192;
            if (k < cnts[c]) tl[n] = taps[(size_t)(ij0 + c) * 192 + k];
        }
        __syncthreads();
#pragma unroll 1
        for (int c = 0; c < 8; ++c) {
            int cnt = cnts[c];
            const int2* tp = &tl[c * 192];
            float a = 0.0f;
#pragma unroll 8
            for (int k = 0; k < cnt; ++k) {
                int2 r = tp[k];
                ushort hv = *(const ushort*)(h2b + (size_t)(uint32)r.y + bo_byte);
                a += __int_as_float(r.x) * bf2f(hv);
            }
            float v = a + bias;
            v = v > 0.0f ? v : 0.0f;
            lout[(j0 + c) * 257 + tid] = f2bf(v);
        }
    }
    __syncthreads();
    // write: 256 rows (bo_local) x 128 ushorts each, packed as 64 uints per row.
    // Each thread owns j-pair (2*lane, 2*lane+1), lane in 0..63; 4 row-groups.
    uint32* cm32 = (uint32*)cm;
    int lane = tid & 63, quarter = tid >> 6;
    for (int rr = 0; rr < 256; rr += 4) {
        int r = rr + quarter;
        ushort u0 = lout[(2 * lane) * 257 + r];
        ushort u1 = lout[(2 * lane + 1) * 257 + r];
        uint32 pr = (uint32)u0 | ((uint32)u1 << 16);
        __builtin_nontemporal_store(pr, &cm32[(size_t)(boT * 256 + r) * 8192 + i * 64 + lane]);
    }
}

// ---------------------------------------------------------------------------
// conv-a: 1x1, 512 -> 128, relu.
// ---------------------------------------------------------------------------
__global__ __launch_bounds__(256) void k_conva(
    const ushort* __restrict__ cm, const float* __restrict__ wa,
    const float* __restrict__ ba, float* __restrict__ p1)
{
    __shared__ float lx[32 * 132];   // [oo][j]
    __shared__ float lwv[32 * 132];  // [oo][c]
    int i = blockIdx.x, b = blockIdx.y;
    int cg = threadIdx.x >> 4, jg = threadIdx.x & 15;
    int c0 = cg * 8, j0 = jg * 8;
    float acc[8][8];
#pragma unroll
    for (int cc = 0; cc < 8; ++cc)
#pragma unroll
        for (int k = 0; k < 8; ++k) acc[cc][k] = 0.0f;

    for (int o0 = 0; o0 < 512; o0 += 32) {
        __syncthreads();
        for (int n = threadIdx.x; n < 512; n += 256) {
            int oo = n >> 4, q = n & 15;
            uint4 v = *(const uint4*)(cm + (size_t)(b * 512 + o0 + oo) * 16384 + i * 128 + q * 8);
            float* dst = &lx[oo * 132 + q * 8];
            dst[0] = bf2f((ushort)(v.x & 0xffffu)); dst[1] = bf2f((ushort)(v.x >> 16));
            dst[2] = bf2f((ushort)(v.y & 0xffffu)); dst[3] = bf2f((ushort)(v.y >> 16));
            dst[4] = bf2f((ushort)(v.z & 0xffffu)); dst[5] = bf2f((ushort)(v.z >> 16));
            dst[6] = bf2f((ushort)(v.w & 0xffffu)); dst[7] = bf2f((ushort)(v.w >> 16));
        }
        for (int n = threadIdx.x; n < 4096; n += 256) {
            int oo = n & 31, c = n >> 5;
            lwv[oo * 132 + c] = wa[(size_t)c * 512 + o0 + oo];
        }
        __syncthreads();
        for (int oo = 0; oo < 32; ++oo) {
            float xv[8], wvv[8];
#pragma unroll
            for (int k = 0; k < 8; ++k) xv[k] = lx[oo * 132 + j0 + k];
#pragma unroll
            for (int k = 0; k < 8; ++k) wvv[k] = lwv[oo * 132 + c0 + k];
#pragma unroll
            for (int cc = 0; cc < 8; ++cc)
#pragma unroll
                for (int k = 0; k < 8; ++k) acc[cc][k] += wvv[cc] * xv[k];
        }
    }
#pragma unroll
    for (int cc = 0; cc < 8; ++cc) {
        float bb = ba[c0 + cc];
#pragma unroll
        for (int k = 0; k < 8; ++k) {
            float v = acc[cc][k] + bb;
            v = v > 0.0f ? v : 0.0f;
            p1[((size_t)(b * 128 + c0 + cc)) * 16384 + i * 128 + j0 + k] = v;
        }
    }
}

// ---------------------------------------------------------------------------
// 3x3 conv, CIN -> 64, pad 1, relu. Stages 8 input channels per barrier.
// ---------------------------------------------------------------------------
template <int CIN>
__global__ __launch_bounds__(256) void k_conv3x3(
    const float* __restrict__ in, const float* __restrict__ w,
    const float* __restrict__ bias, float* __restrict__ out)
{
    __shared__ float lx[8][3 * 132];   // 8 ch x 3 rows, padded cols 0..129
    __shared__ float lws[8][576];      // 8 ch x (64 c_out x 9)
    int i = blockIdx.x, b = blockIdx.y;
    int cg = threadIdx.x >> 4, jg = threadIdx.x & 15;
    int c0 = cg * 4, j0 = jg * 8;
    float acc[4][8];
#pragma unroll
    for (int cc = 0; cc < 4; ++cc)
#pragma unroll
        for (int k = 0; k < 8; ++k) acc[cc][k] = 0.0f;

    for (int o0 = 0; o0 < CIN; o0 += 8) {
        __syncthreads();
        for (int n = threadIdx.x; n < 8 * 390; n += 256) {
            int ch = n / 390, m = n - ch * 390;
            int r = m / 130, col = m - r * 130;
            int ii = i + r - 1, jj = col - 1;
            float v = 0.0f;
            if (ii >= 0 && ii < 128 && jj >= 0 && jj < 128)
                v = in[((size_t)(b * CIN + o0 + ch) * 128 + ii) * 128 + jj];
            lx[ch][r * 132 + col] = v;
        }
        for (int n = threadIdx.x; n < 8 * 576; n += 256) {
            int ch = n / 576, m = n - ch * 576;
            lws[ch][m] = w[((size_t)(m / 9) * CIN + o0 + ch) * 9 + (m % 9)];
        }
        __syncthreads();

#pragma unroll 1
        for (int ch = 0; ch < 8; ++ch) {
            float x0[10], x1[10], x2[10];
#pragma unroll
            for (int k = 0; k < 10; ++k) {
                x0[k] = lx[ch][0 * 132 + j0 + k];
                x1[k] = lx[ch][1 * 132 + j0 + k];
                x2[k] = lx[ch][2 * 132 + j0 + k];
            }
#pragma unroll
            for (int cc = 0; cc < 4; ++cc) {
                const float* wp = &lws[ch][(c0 + cc) * 9];
                float w00 = wp[0], w01 = wp[1], w02 = wp[2];
                float w10 = wp[3], w11 = wp[4], w12 = wp[5];
                float w20 = wp[6], w21 = wp[7], w22 = wp[8];
#pragma unroll
                for (int k = 0; k < 8; ++k) {
                    acc[cc][k] += w00 * x0[k] + w01 * x0[k + 1] + w02 * x0[k + 2]
                                + w10 * x1[k] + w11 * x1[k + 1] + w12 * x1[k + 2]
                                + w20 * x2[k] + w21 * x2[k + 1] + w22 * x2[k + 2];
                }
            }
        }
    }
#pragma unroll
    for (int cc = 0; cc < 4; ++cc) {
        float bb = bias[c0 + cc];
#pragma unroll
        for (int k = 0; k < 8; ++k) {
            float v = acc[cc][k] + bb;
            v = v > 0.0f ? v : 0.0f;
            out[((size_t)(b * 64 + c0 + cc) * 128 + i) * 128 + j0 + k] = v;
        }
    }
}

// ---------------------------------------------------------------------------
// conv-d: 1x1, 64 -> 4, sigmoid, scatter to d_out floats
// ---------------------------------------------------------------------------
__global__ __launch_bounds__(256) void k_convd(
    const float* __restrict__ p3, const float* __restrict__ wd,
    const float* __restrict__ bd, float* __restrict__ outp)
{
    __shared__ float lw[256];
    int b = blockIdx.y;
    int ij = blockIdx.x * 256 + threadIdx.x;
    lw[threadIdx.x] = wd[threadIdx.x];
    __syncthreads();
    float a0 = bd[0], a1 = bd[1], a2 = bd[2], a3 = bd[3];
    for (int c = 0; c < 64; ++c) {
        float v = p3[((size_t)(b * 64 + c)) * 16384 + ij];
        a0 += lw[c] * v;
        a1 += lw[64 + c] * v;
        a2 += lw[128 + c] * v;
        a3 += lw[192 + c] * v;
    }
    outp[1536 + (size_t)(b * 2 + 0) * 16384 + ij] = sigmoidf(a2);  // iou ch0
    outp[1536 + (size_t)(b * 2 + 1) * 16384 + ij] = sigmoidf(a3);  // iou ch1
    outp[132608 + (size_t)b * 16384 + ij] = sigmoidf(a0);          // prop_start
    outp[198144 + (size_t)b * 16384 + ij] = sigmoidf(a1);          // prop_end
}

// ---------------------------------------------------------------------------
extern "C" void kernel_launch(void* const* d_in, const int* in_sizes, int n_in,
                              void* d_out, int out_size, void* d_ws, size_t ws_size,
                              hipStream_t stream)
{
    const float* x   = (const float*)d_in[0];
    const float* w1  = (const float*)d_in[1];
    const float* b1  = (const float*)d_in[2];
    const float* w2  = (const float*)d_in[3];
    const float* b2  = (const float*)d_in[4];
    const float* w3  = (const float*)d_in[5];
    const float* b3  = (const float*)d_in[6];
    const float* w3d = (const float*)d_in[7];
    const float* b3d = (const float*)d_in[8];
    const float* wa  = (const float*)d_in[9];
    const float* ba  = (const float*)d_in[10];
    const float* wb  = (const float*)d_in[11];
    const float* bb  = (const float*)d_in[12];
    const float* wc  = (const float*)d_in[13];
    const float* bc  = (const float*)d_in[14];
    const float* wd  = (const float*)d_in[15];
    const float* bd  = (const float*)d_in[16];
    const float* sm  = (const float*)d_in[17];
    float* outp = (float*)d_out;
    char* ws = (char*)d_ws;

    // workspace layout (with aliasing; peak ~127.3 MB)
    float*  h1    = (float*)(ws + 0);              //  1,048,576 B
    float*  h     = (float*)(ws + 1048576);        //    262,144 B
    ushort* h2t   = (ushort*)(ws + 1310720);       // 16,777,216 B
    uint32* ecnt  = (uint32*)(ws + 18087936);      //  2,097,152 B
    uint8_t* et   = (uint8_t*)(ws + 20185088);     //  4,194,304 B
    float*  ewf   = (float*)(ws + 24379392);       // 16,777,216 B
    uint32* cntij = (uint32*)(ws + 41156608);      //     65,536 B
    int2*   taps  = (int2*)(ws + 41222144);        // 25,165,824 B
    ushort* cm    = (ushort*)(ws + 66387968);      // 67,108,864 B  -> ends 133,496,832
    float*  p1    = (float*)(ws + 1310720);        // 33,554,432 B (aliases h2t+e-bufs; dead then)
    float*  p2    = (float*)(ws + 41222144);       // 16,777,216 B (aliases taps; dead then)
    float*  p3    = (float*)(ws + 66387968);       // 16,777,216 B (aliases cm; dead then)

    dim3 blk(256);
    k_conv1d_relu<<<dim3(32, 4), blk, 0, stream>>>(x, w1, b1, h1, 200, 400, 512);
    k_conv1d_relu<<<dim3(8, 4), blk, 0, stream>>>(h1, w2, b2, h, 512, 512, 128);
    k_x4<<<1, 512, 0, stream>>>(h, w3, b3, outp);
    k_h2<<<dim3(8, 32, 4), blk, 0, stream>>>(h, w3d, h2t);
    k_e1<<<2048, blk, 0, stream>>>(sm, ecnt, et, ewf);
    k_e2<<<8192, 64, 0, stream>>>(ecnt, et, ewf, cntij, taps);
    k_bm<<<dim3(8, 128), blk, 0, stream>>>(h2t, taps, cntij, b3d, cm);
    k_conva<<<dim3(128, 4), blk, 0, stream>>>(cm, wa, ba, p1);
    k_conv3x3<128><<<dim3(128, 4), blk, 0, stream>>>(p1, wb, bb, p2);
    k_conv3x3<64><<<dim3(128, 4), blk, 0, stream>>>(p2, wc, bc, p3);
    k_convd<<<dim3(64, 4), blk, 0, stream>>>(p3, wd, bd, outp);
}

// Round 5
// 1228.615 us; speedup vs baseline: 1.6668x; 1.0860x over previous
//
#include <hip/hip_runtime.h>
#include <hip/hip_bf16.h>
#include <stdint.h>

// ---------------------------------------------------------------------------
// Problem geometry
//   x (4,400,128) -> conv1d(200->512,k3,p1,relu) -> conv1d(512->128,k3,p1,relu) = h
//   x4 = sigmoid(0.01*conv1d(h, w3(3,128,1))) -> outputs xc(ch2), xb_start(ch0), xb_end(ch1)
//   cm = einsum('bct,tm->bcm', h, mask) ; conv3d(w3d, stride 32) + b3d, relu
//     == relu(b3d[o] + sum_{s,t} mask[t,s,i,j] * H2[b,o,s,t]),
//        H2[b,o,s,t] = sum_c w3d[o,c,s] * h[b,c,t]      (mask: <=6 taps per (s,i,j))
//   then 1x1(512->128,relu), 3x3(128->64,relu), 3x3(64->64,relu), 1x1(64->4,sigmoid)
//   outputs (float32): xc,xb_start,xb_end (3*512) | iou (4,2,128,128) | prop_start | prop_end
//
// cm is stored TRANSPOSED: cm2[ij][bo] (ij = i*128+j fastest-varying over bo)
// so k_bm stores coalesced without an LDS transpose stage.
// ---------------------------------------------------------------------------

typedef unsigned int uint32;

__device__ __forceinline__ float bf2f(ushort u) {
    return __uint_as_float(((uint32)u) << 16);
}
__device__ __forceinline__ ushort f2bf(float f) {
    uint32 x = __float_as_uint(f);
    uint32 r = (x + 0x7FFFu + ((x >> 16) & 1u)) >> 16;
    return (ushort)r;
}
__device__ __forceinline__ float sigmoidf(float x) {
    return 1.0f / (1.0f + __expf(-x));
}

// ---------------------------------------------------------------------------
// conv1d (k=3, pad=1, relu). Block: 16 out-channels x 128 t. Grid (COUT/16, B).
// ---------------------------------------------------------------------------
__global__ __launch_bounds__(256) void k_conv1d_relu(
    const float* __restrict__ in, const float* __restrict__ w,
    const float* __restrict__ bias, float* __restrict__ out,
    int CIN, int in_batch_stride, int COUT)
{
    __shared__ float lx[64 * 132];   // [c][0..127 data, 128 = zero pad]
    int b  = blockIdx.y;
    int o  = blockIdx.x * 16 + (threadIdx.x >> 4);
    int tg = threadIdx.x & 15;
    int t0 = tg * 8;

    float acc[8];
#pragma unroll
    for (int k = 0; k < 8; ++k) acc[k] = 0.0f;

    for (int c0 = 0; c0 < CIN; c0 += 64) {
        int nc = CIN - c0; if (nc > 64) nc = 64;
        __syncthreads();
        for (int n = threadIdx.x; n < nc * 32; n += 256) {
            int cl = n >> 5, q = n & 31;
            float4 v = *(const float4*)(in + ((size_t)(b * in_batch_stride + c0 + cl)) * 128 + q * 4);
            *(float4*)(&lx[cl * 132 + q * 4]) = v;
        }
        for (int cl = threadIdx.x; cl < nc; cl += 256) lx[cl * 132 + 128] = 0.0f;
        __syncthreads();

        for (int cl = 0; cl < nc; ++cl) {
            int c = c0 + cl;
            const float* wp = w + ((size_t)o * CIN + c) * 3;
            float w0 = wp[0], w1 = wp[1], w2 = wp[2];
            const float* row = &lx[cl * 132];
            float xv[10];
            if (t0 == 0) {
                xv[0] = 0.0f;
#pragma unroll
                for (int k = 1; k < 10; ++k) xv[k] = row[k - 1];
            } else {
#pragma unroll
                for (int k = 0; k < 10; ++k) xv[k] = row[t0 - 1 + k];
            }
#pragma unroll
            for (int k = 0; k < 8; ++k)
                acc[k] += w0 * xv[k] + w1 * xv[k + 1] + w2 * xv[k + 2];
        }
    }
    float bo = bias[o];
#pragma unroll
    for (int k = 0; k < 8; ++k) {
        float v = acc[k] + bo;
        out[((size_t)(b * COUT + o)) * 128 + t0 + k] = v > 0.0f ? v : 0.0f;
    }
}

// ---------------------------------------------------------------------------
// x4 head -> d_out[0:1536] floats: (xc=ch2 | xb_start=ch0 | xb_end=ch1)
// ---------------------------------------------------------------------------
__global__ void k_x4(const float* __restrict__ h, const float* __restrict__ w3,
                     const float* __restrict__ b3, float* __restrict__ outp)
{
    int tid = threadIdx.x;
    int b = tid >> 7, t = tid & 127;
    float a0 = 0.f, a1 = 0.f, a2 = 0.f;
    for (int c = 0; c < 128; ++c) {
        float hv = h[((size_t)(b * 128 + c)) * 128 + t];
        a0 += w3[c] * hv;
        a1 += w3[128 + c] * hv;
        a2 += w3[256 + c] * hv;
    }
    float s0 = sigmoidf(0.01f * (a0 + b3[0]));
    float s1 = sigmoidf(0.01f * (a1 + b3[1]));
    float s2 = sigmoidf(0.01f * (a2 + b3[2]));
    int bt = b * 128 + t;
    outp[bt]        = s2;   // xc
    outp[512 + bt]  = s0;   // xb_start
    outp[1024 + bt] = s1;   // xb_end
}

// ---------------------------------------------------------------------------
// H2t[(s*128+t)*2048 + b*512+o] = bf16( sum_c w3d[o,c,s]*h[b,c,t] )
// ---------------------------------------------------------------------------
__global__ __launch_bounds__(256) void k_h2(
    const float* __restrict__ h, const float* __restrict__ w3d,
    ushort* __restrict__ h2t)
{
    __shared__ float lw[64 * 129];     // [o][c]
    __shared__ float lhs[32 * 132];    // [c_local][t] ; reused as ushort out stage
    int ot = blockIdx.x, s = blockIdx.y, b = blockIdx.z;
    int o0 = ot * 64;

    for (int n = threadIdx.x; n < 8192; n += 256) {
        int o = n >> 7, c = n & 127;
        lw[o * 129 + c] = w3d[(size_t)(o0 + o) * 4096 + c * 32 + s];
    }

    int og = threadIdx.x >> 4, tg = threadIdx.x & 15;
    int o0t = og * 4, t0 = tg * 8;
    float acc[4][8];
#pragma unroll
    for (int oo = 0; oo < 4; ++oo)
#pragma unroll
        for (int k = 0; k < 8; ++k) acc[oo][k] = 0.0f;

    for (int c0 = 0; c0 < 128; c0 += 32) {
        __syncthreads();
        for (int n = threadIdx.x; n < 1024; n += 256) {
            int cl = n >> 5, q = n & 31;
            *(float4*)(&lhs[cl * 132 + q * 4]) =
                *(const float4*)(h + ((size_t)(b * 128 + c0 + cl)) * 128 + q * 4);
        }
        __syncthreads();
        for (int cl = 0; cl < 32; ++cl) {
            float hv[8];
#pragma unroll
            for (int k = 0; k < 8; ++k) hv[k] = lhs[cl * 132 + t0 + k];
#pragma unroll
            for (int oo = 0; oo < 4; ++oo) {
                float wv = lw[(o0t + oo) * 129 + c0 + cl];
#pragma unroll
                for (int k = 0; k < 8; ++k) acc[oo][k] += wv * hv[k];
            }
        }
    }
    __syncthreads();
    ushort* lout = (ushort*)lhs;       // [t*64 + o]
#pragma unroll
    for (int oo = 0; oo < 4; ++oo)
#pragma unroll
        for (int k = 0; k < 8; ++k)
            lout[(t0 + k) * 64 + o0t + oo] = f2bf(acc[oo][k]);
    __syncthreads();
    for (int n = threadIdx.x; n < 8192; n += 256) {
        int t = n >> 6, o = n & 63;
        h2t[(size_t)(s * 128 + t) * 2048 + b * 512 + o0 + o] = lout[n];
    }
}

// ---------------------------------------------------------------------------
// E1: per mask column m=(s,i,j), collect nonzero (t,w) taps (<=6 exist, cap 8).
// ---------------------------------------------------------------------------
__global__ __launch_bounds__(256) void k_e1(
    const float* __restrict__ mask, uint32* __restrict__ ecnt,
    uint8_t* __restrict__ et, float* __restrict__ ew)
{
    uint32 m = blockIdx.x * 256 + threadIdx.x;
    int cnt = 0;
    for (int t = 0; t < 128; ++t) {
        float w = mask[(size_t)t * 524288 + m];
        if (w != 0.0f) {
            if (cnt < 8) {
                et[(size_t)m * 8 + cnt] = (uint8_t)t;
                ew[(size_t)m * 8 + cnt] = w;
            }
            cnt++;
        }
    }
    ecnt[m] = (uint32)(cnt < 8 ? cnt : 8);
}

// ---------------------------------------------------------------------------
// E2: merge per (i,j): taps over all 32 s -> packed {w_bits, byte_off} (<=192).
// byte_off = st * 4096 (h2t row pitch in bytes) so k_bm's inner loop is lean.
// ---------------------------------------------------------------------------
__global__ void k_e2(const uint32* __restrict__ ecnt, const uint8_t* __restrict__ et,
                     const float* __restrict__ ew, uint32* __restrict__ cntij,
                     int2* __restrict__ taps)
{
    int lane = threadIdx.x & 31;
    int col = blockIdx.x * 2 + (threadIdx.x >> 5);
    uint32 m = (uint32)lane * 16384u + (uint32)col;
    int c = (int)ecnt[m];
    int v = c;
    for (int d = 1; d < 32; d <<= 1) {
        int t = __shfl_up(v, d, 32);
        if (lane >= d) v += t;
    }
    int off = v - c;
    if (lane == 31) cntij[col] = (uint32)v;
    for (int k = 0; k < c; ++k) {
        int2 r;
        r.x = __float_as_int(ew[(size_t)m * 8 + k]);
        r.y = ((lane << 7) + (int)et[(size_t)m * 8 + k]) << 12;   // st * 4096 bytes
        taps[(size_t)col * 192 + off + k] = r;
    }
}

// ---------------------------------------------------------------------------
// k_bm: cm2[ij, bo] = relu(b3d[o] + sum_taps w * H2t[st, bo])   (bf16 out)
// Grid (x=boT 8, y=i 128): x fastest -> round-robin pins each bo-slice (2 MB of
// h2t) to one XCD's L2. Direct coalesced nontemporal stores (no LDS transpose):
// LDS = 12 KB -> 4 blocks/CU (grid-limited), 16 waves for latency hiding.
// ---------------------------------------------------------------------------
__global__ __launch_bounds__(256) void k_bm(
    const ushort* __restrict__ h2t, const int2* __restrict__ taps,
    const uint32* __restrict__ cntij, const float* __restrict__ b3d,
    ushort* __restrict__ cm2)
{
    __shared__ int2 tl[8 * 192];        // 12,288 B
    int boT = blockIdx.x, i = blockIdx.y;
    int tid = threadIdx.x;
    int bo = boT * 256 + tid;
    uint32 bo_byte = (uint32)bo * 2u;
    float bias = b3d[bo & 511];
    const char* h2b = (const char*)h2t;

    for (int jc = 0; jc < 16; ++jc) {
        int j0 = jc * 8;
        int ij0 = i * 128 + j0;
        int cnts[8];
#pragma unroll
        for (int c = 0; c < 8; ++c) cnts[c] = (int)cntij[ij0 + c];
        __syncthreads();   // previous chunk's readers done before tl overwrite
        for (int n = tid; n < 1536; n += 256) {
            int c = n / 192, k = n - c * 192;
            if (k < cnts[c]) tl[n] = taps[(size_t)(ij0 + c) * 192 + k];
        }
        __syncthreads();
#pragma unroll 1
        for (int c = 0; c < 8; ++c) {
            int cnt = cnts[c];
            const int2* tp = &tl[c * 192];
            float a = 0.0f;
#pragma unroll 16
            for (int k = 0; k < cnt; ++k) {
                int2 r = tp[k];
                ushort hv = *(const ushort*)(h2b + ((uint32)r.y + bo_byte));
                a += __int_as_float(r.x) * bf2f(hv);
            }
            float v = a + bias;
            v = v > 0.0f ? v : 0.0f;
            __builtin_nontemporal_store(f2bf(v), &cm2[(size_t)(ij0 + c) * 2048 + bo]);
        }
    }
}

// ---------------------------------------------------------------------------
// conv-a: 1x1, 512 -> 128, relu.  Reads cm2[ij][bo] layout.
// p1[b,c,ij] = relu(ba[c] + sum_o wa[c,o]*cm2[ij, b*512+o])
// ---------------------------------------------------------------------------
__global__ __launch_bounds__(256) void k_conva(
    const ushort* __restrict__ cm2, const float* __restrict__ wa,
    const float* __restrict__ ba, float* __restrict__ p1)
{
    __shared__ float lx[32 * 132];   // [oo][j]
    __shared__ float lwv[32 * 132];  // [oo][c]
    int i = blockIdx.x, b = blockIdx.y;
    int cg = threadIdx.x >> 4, jg = threadIdx.x & 15;
    int c0 = cg * 8, j0 = jg * 8;
    float acc[8][8];
#pragma unroll
    for (int cc = 0; cc < 8; ++cc)
#pragma unroll
        for (int k = 0; k < 8; ++k) acc[cc][k] = 0.0f;

    for (int o0 = 0; o0 < 512; o0 += 32) {
        __syncthreads();
        // stage 128 j x 32 o from cm2[(i*128+j)*2048 + b*512 + o0 + *]
        for (int n = threadIdx.x; n < 2048; n += 256) {
            int j = n >> 4, q = n & 15;            // q = o-pair index
            uint32 v = *(const uint32*)(cm2 + ((size_t)(i * 128 + j)) * 2048 + b * 512 + o0 + 2 * q);
            lx[(2 * q) * 132 + j]     = bf2f((ushort)(v & 0xffffu));
            lx[(2 * q + 1) * 132 + j] = bf2f((ushort)(v >> 16));
        }
        for (int n = threadIdx.x; n < 4096; n += 256) {
            int oo = n & 31, c = n >> 5;
            lwv[oo * 132 + c] = wa[(size_t)c * 512 + o0 + oo];
        }
        __syncthreads();
        for (int oo = 0; oo < 32; ++oo) {
            float xv[8], wvv[8];
#pragma unroll
            for (int k = 0; k < 8; ++k) xv[k] = lx[oo * 132 + j0 + k];
#pragma unroll
            for (int k = 0; k < 8; ++k) wvv[k] = lwv[oo * 132 + c0 + k];
#pragma unroll
            for (int cc = 0; cc < 8; ++cc)
#pragma unroll
                for (int k = 0; k < 8; ++k) acc[cc][k] += wvv[cc] * xv[k];
        }
    }
#pragma unroll
    for (int cc = 0; cc < 8; ++cc) {
        float bb = ba[c0 + cc];
#pragma unroll
        for (int k = 0; k < 8; ++k) {
            float v = acc[cc][k] + bb;
            v = v > 0.0f ? v : 0.0f;
            p1[((size_t)(b * 128 + c0 + cc)) * 16384 + i * 128 + j0 + k] = v;
        }
    }
}

// ---------------------------------------------------------------------------
// 3x3 conv, CIN -> 64, pad 1, relu. Stages 8 input channels per barrier.
// ---------------------------------------------------------------------------
template <int CIN>
__global__ __launch_bounds__(256) void k_conv3x3(
    const float* __restrict__ in, const float* __restrict__ w,
    const float* __restrict__ bias, float* __restrict__ out)
{
    __shared__ float lx[8][3 * 132];   // 8 ch x 3 rows, padded cols 0..129
    __shared__ float lws[8][576];      // 8 ch x (64 c_out x 9)
    int i = blockIdx.x, b = blockIdx.y;
    int cg = threadIdx.x >> 4, jg = threadIdx.x & 15;
    int c0 = cg * 4, j0 = jg * 8;
    float acc[4][8];
#pragma unroll
    for (int cc = 0; cc < 4; ++cc)
#pragma unroll
        for (int k = 0; k < 8; ++k) acc[cc][k] = 0.0f;

    for (int o0 = 0; o0 < CIN; o0 += 8) {
        __syncthreads();
        for (int n = threadIdx.x; n < 8 * 390; n += 256) {
            int ch = n / 390, m = n - ch * 390;
            int r = m / 130, col = m - r * 130;
            int ii = i + r - 1, jj = col - 1;
            float v = 0.0f;
            if (ii >= 0 && ii < 128 && jj >= 0 && jj < 128)
                v = in[((size_t)(b * CIN + o0 + ch) * 128 + ii) * 128 + jj];
            lx[ch][r * 132 + col] = v;
        }
        for (int n = threadIdx.x; n < 8 * 576; n += 256) {
            int ch = n / 576, m = n - ch * 576;
            lws[ch][m] = w[((size_t)(m / 9) * CIN + o0 + ch) * 9 + (m % 9)];
        }
        __syncthreads();

#pragma unroll 1
        for (int ch = 0; ch < 8; ++ch) {
            float x0[10], x1[10], x2[10];
#pragma unroll
            for (int k = 0; k < 10; ++k) {
                x0[k] = lx[ch][0 * 132 + j0 + k];
                x1[k] = lx[ch][1 * 132 + j0 + k];
                x2[k] = lx[ch][2 * 132 + j0 + k];
            }
#pragma unroll
            for (int cc = 0; cc < 4; ++cc) {
                const float* wp = &lws[ch][(c0 + cc) * 9];
                float w00 = wp[0], w01 = wp[1], w02 = wp[2];
                float w10 = wp[3], w11 = wp[4], w12 = wp[5];
                float w20 = wp[6], w21 = wp[7], w22 = wp[8];
#pragma unroll
                for (int k = 0; k < 8; ++k) {
                    acc[cc][k] += w00 * x0[k] + w01 * x0[k + 1] + w02 * x0[k + 2]
                                + w10 * x1[k] + w11 * x1[k + 1] + w12 * x1[k + 2]
                                + w20 * x2[k] + w21 * x2[k + 1] + w22 * x2[k + 2];
                }
            }
        }
    }
#pragma unroll
    for (int cc = 0; cc < 4; ++cc) {
        float bb = bias[c0 + cc];
#pragma unroll
        for (int k = 0; k < 8; ++k) {
            float v = acc[cc][k] + bb;
            v = v > 0.0f ? v : 0.0f;
            out[((size_t)(b * 64 + c0 + cc) * 128 + i) * 128 + j0 + k] = v;
        }
    }
}

// ---------------------------------------------------------------------------
// conv-d: 1x1, 64 -> 4, sigmoid, scatter to d_out floats
// ---------------------------------------------------------------------------
__global__ __launch_bounds__(256) void k_convd(
    const float* __restrict__ p3, const float* __restrict__ wd,
    const float* __restrict__ bd, float* __restrict__ outp)
{
    __shared__ float lw[256];
    int b = blockIdx.y;
    int ij = blockIdx.x * 256 + threadIdx.x;
    lw[threadIdx.x] = wd[threadIdx.x];
    __syncthreads();
    float a0 = bd[0], a1 = bd[1], a2 = bd[2], a3 = bd[3];
    for (int c = 0; c < 64; ++c) {
        float v = p3[((size_t)(b * 64 + c)) * 16384 + ij];
        a0 += lw[c] * v;
        a1 += lw[64 + c] * v;
        a2 += lw[128 + c] * v;
        a3 += lw[192 + c] * v;
    }
    outp[1536 + (size_t)(b * 2 + 0) * 16384 + ij] = sigmoidf(a2);  // iou ch0
    outp[1536 + (size_t)(b * 2 + 1) * 16384 + ij] = sigmoidf(a3);  // iou ch1
    outp[132608 + (size_t)b * 16384 + ij] = sigmoidf(a0);          // prop_start
    outp[198144 + (size_t)b * 16384 + ij] = sigmoidf(a1);          // prop_end
}

// ---------------------------------------------------------------------------
extern "C" void kernel_launch(void* const* d_in, const int* in_sizes, int n_in,
                              void* d_out, int out_size, void* d_ws, size_t ws_size,
                              hipStream_t stream)
{
    const float* x   = (const float*)d_in[0];
    const float* w1  = (const float*)d_in[1];
    const float* b1  = (const float*)d_in[2];
    const float* w2  = (const float*)d_in[3];
    const float* b2  = (const float*)d_in[4];
    const float* w3  = (const float*)d_in[5];
    const float* b3  = (const float*)d_in[6];
    const float* w3d = (const float*)d_in[7];
    const float* b3d = (const float*)d_in[8];
    const float* wa  = (const float*)d_in[9];
    const float* ba  = (const float*)d_in[10];
    const float* wb  = (const float*)d_in[11];
    const float* bb  = (const float*)d_in[12];
    const float* wc  = (const float*)d_in[13];
    const float* bc  = (const float*)d_in[14];
    const float* wd  = (const float*)d_in[15];
    const float* bd  = (const float*)d_in[16];
    const float* sm  = (const float*)d_in[17];
    float* outp = (float*)d_out;
    char* ws = (char*)d_ws;

    // workspace layout (with aliasing; peak ~127.3 MB)
    float*  h1    = (float*)(ws + 0);              //  1,048,576 B
    float*  h     = (float*)(ws + 1048576);        //    262,144 B
    ushort* h2t   = (ushort*)(ws + 1310720);       // 16,777,216 B
    uint32* ecnt  = (uint32*)(ws + 18087936);      //  2,097,152 B
    uint8_t* et   = (uint8_t*)(ws + 20185088);     //  4,194,304 B
    float*  ewf   = (float*)(ws + 24379392);       // 16,777,216 B
    uint32* cntij = (uint32*)(ws + 41156608);      //     65,536 B
    int2*   taps  = (int2*)(ws + 41222144);        // 25,165,824 B
    ushort* cm2   = (ushort*)(ws + 66387968);      // 67,108,864 B  [ij][bo]
    float*  p1    = (float*)(ws + 1310720);        // 33,554,432 B (aliases h2t+e-bufs; dead then)
    float*  p2    = (float*)(ws + 41222144);       // 16,777,216 B (aliases taps; dead then)
    float*  p3    = (float*)(ws + 66387968);       // 16,777,216 B (aliases cm2; dead then)

    dim3 blk(256);
    k_conv1d_relu<<<dim3(32, 4), blk, 0, stream>>>(x, w1, b1, h1, 200, 400, 512);
    k_conv1d_relu<<<dim3(8, 4), blk, 0, stream>>>(h1, w2, b2, h, 512, 512, 128);
    k_x4<<<1, 512, 0, stream>>>(h, w3, b3, outp);
    k_h2<<<dim3(8, 32, 4), blk, 0, stream>>>(h, w3d, h2t);
    k_e1<<<2048, blk, 0, stream>>>(sm, ecnt, et, ewf);
    k_e2<<<8192, 64, 0, stream>>>(ecnt, et, ewf, cntij, taps);
    k_bm<<<dim3(8, 128), blk, 0, stream>>>(h2t, taps, cntij, b3d, cm2);
    k_conva<<<dim3(128, 4), blk, 0, stream>>>(cm2, wa, ba, p1);
    k_conv3x3<128><<<dim3(128, 4), blk, 0, stream>>>(p1, wb, bb, p2);
    k_conv3x3<64><<<dim3(128, 4), blk, 0, stream>>>(p2, wc, bc, p3);
    k_convd<<<dim3(64, 4), blk, 0, stream>>>(p3, wd, bd, outp);
}

// Round 6
// 1208.215 us; speedup vs baseline: 1.6950x; 1.0169x over previous
//
#include <hip/hip_runtime.h>
#include <hip/hip_bf16.h>
#include <stdint.h>

// ---------------------------------------------------------------------------
// Problem geometry
//   x (4,400,128) -> conv1d(200->512,k3,p1,relu) -> conv1d(512->128,k3,p1,relu) = h
//   x4 = sigmoid(0.01*conv1d(h, w3(3,128,1))) -> outputs xc(ch2), xb_start(ch0), xb_end(ch1)
//   cm = einsum('bct,tm->bcm', h, mask) ; conv3d(w3d, stride 32) + b3d, relu
//     == relu(b3d[o] + sum_{s,t} mask[t,s,i,j] * H2[b,o,s,t]),
//        H2[b,o,s,t] = sum_c w3d[o,c,s] * h[b,c,t]      (mask: <=6 taps per (s,i,j))
//   then 1x1(512->128,relu), 3x3(128->64,relu), 3x3(64->64,relu), 1x1(64->4,sigmoid)
//   outputs (float32): xc,xb_start,xb_end (3*512) | iou (4,2,128,128) | prop_start | prop_end
//
// cm is stored TRANSPOSED: cm2[ij][bo] so k_bm stores coalesced directly.
// k_bm grid: (x=boT 8 -> XCD-pinned h2t slice, y = i*2 + j-half) for 8 blk/CU.
// ---------------------------------------------------------------------------

typedef unsigned int uint32;

__device__ __forceinline__ float bf2f(ushort u) {
    return __uint_as_float(((uint32)u) << 16);
}
__device__ __forceinline__ ushort f2bf(float f) {
    uint32 x = __float_as_uint(f);
    uint32 r = (x + 0x7FFFu + ((x >> 16) & 1u)) >> 16;
    return (ushort)r;
}
__device__ __forceinline__ float sigmoidf(float x) {
    return 1.0f / (1.0f + __expf(-x));
}

// ---------------------------------------------------------------------------
// conv1d (k=3, pad=1, relu). Block: 16 out-channels x 128 t. Grid (COUT/16, B).
// ---------------------------------------------------------------------------
__global__ __launch_bounds__(256) void k_conv1d_relu(
    const float* __restrict__ in, const float* __restrict__ w,
    const float* __restrict__ bias, float* __restrict__ out,
    int CIN, int in_batch_stride, int COUT)
{
    __shared__ float lx[64 * 132];   // [c][0..127 data, 128 = zero pad]
    int b  = blockIdx.y;
    int o  = blockIdx.x * 16 + (threadIdx.x >> 4);
    int tg = threadIdx.x & 15;
    int t0 = tg * 8;

    float acc[8];
#pragma unroll
    for (int k = 0; k < 8; ++k) acc[k] = 0.0f;

    for (int c0 = 0; c0 < CIN; c0 += 64) {
        int nc = CIN - c0; if (nc > 64) nc = 64;
        __syncthreads();
        for (int n = threadIdx.x; n < nc * 32; n += 256) {
            int cl = n >> 5, q = n & 31;
            float4 v = *(const float4*)(in + ((size_t)(b * in_batch_stride + c0 + cl)) * 128 + q * 4);
            *(float4*)(&lx[cl * 132 + q * 4]) = v;
        }
        for (int cl = threadIdx.x; cl < nc; cl += 256) lx[cl * 132 + 128] = 0.0f;
        __syncthreads();

        for (int cl = 0; cl < nc; ++cl) {
            int c = c0 + cl;
            const float* wp = w + ((size_t)o * CIN + c) * 3;
            float w0 = wp[0], w1 = wp[1], w2 = wp[2];
            const float* row = &lx[cl * 132];
            float xv[10];
            if (t0 == 0) {
                xv[0] = 0.0f;
#pragma unroll
                for (int k = 1; k < 10; ++k) xv[k] = row[k - 1];
            } else {
#pragma unroll
                for (int k = 0; k < 10; ++k) xv[k] = row[t0 - 1 + k];
            }
#pragma unroll
            for (int k = 0; k < 8; ++k)
                acc[k] += w0 * xv[k] + w1 * xv[k + 1] + w2 * xv[k + 2];
        }
    }
    float bo = bias[o];
#pragma unroll
    for (int k = 0; k < 8; ++k) {
        float v = acc[k] + bo;
        out[((size_t)(b * COUT + o)) * 128 + t0 + k] = v > 0.0f ? v : 0.0f;
    }
}

// ---------------------------------------------------------------------------
// x4 head -> d_out[0:1536] floats: (xc=ch2 | xb_start=ch0 | xb_end=ch1)
// ---------------------------------------------------------------------------
__global__ void k_x4(const float* __restrict__ h, const float* __restrict__ w3,
                     const float* __restrict__ b3, float* __restrict__ outp)
{
    int tid = threadIdx.x;
    int b = tid >> 7, t = tid & 127;
    float a0 = 0.f, a1 = 0.f, a2 = 0.f;
    for (int c = 0; c < 128; ++c) {
        float hv = h[((size_t)(b * 128 + c)) * 128 + t];
        a0 += w3[c] * hv;
        a1 += w3[128 + c] * hv;
        a2 += w3[256 + c] * hv;
    }
    float s0 = sigmoidf(0.01f * (a0 + b3[0]));
    float s1 = sigmoidf(0.01f * (a1 + b3[1]));
    float s2 = sigmoidf(0.01f * (a2 + b3[2]));
    int bt = b * 128 + t;
    outp[bt]        = s2;   // xc
    outp[512 + bt]  = s0;   // xb_start
    outp[1024 + bt] = s1;   // xb_end
}

// ---------------------------------------------------------------------------
// H2t[(s*128+t)*2048 + b*512+o] = bf16( sum_c w3d[o,c,s]*h[b,c,t] )
// ---------------------------------------------------------------------------
__global__ __launch_bounds__(256) void k_h2(
    const float* __restrict__ h, const float* __restrict__ w3d,
    ushort* __restrict__ h2t)
{
    __shared__ float lw[64 * 129];     // [o][c]
    __shared__ float lhs[32 * 132];    // [c_local][t] ; reused as ushort out stage
    int ot = blockIdx.x, s = blockIdx.y, b = blockIdx.z;
    int o0 = ot * 64;

    for (int n = threadIdx.x; n < 8192; n += 256) {
        int o = n >> 7, c = n & 127;
        lw[o * 129 + c] = w3d[(size_t)(o0 + o) * 4096 + c * 32 + s];
    }

    int og = threadIdx.x >> 4, tg = threadIdx.x & 15;
    int o0t = og * 4, t0 = tg * 8;
    float acc[4][8];
#pragma unroll
    for (int oo = 0; oo < 4; ++oo)
#pragma unroll
        for (int k = 0; k < 8; ++k) acc[oo][k] = 0.0f;

    for (int c0 = 0; c0 < 128; c0 += 32) {
        __syncthreads();
        for (int n = threadIdx.x; n < 1024; n += 256) {
            int cl = n >> 5, q = n & 31;
            *(float4*)(&lhs[cl * 132 + q * 4]) =
                *(const float4*)(h + ((size_t)(b * 128 + c0 + cl)) * 128 + q * 4);
        }
        __syncthreads();
        for (int cl = 0; cl < 32; ++cl) {
            float hv[8];
#pragma unroll
            for (int k = 0; k < 8; ++k) hv[k] = lhs[cl * 132 + t0 + k];
#pragma unroll
            for (int oo = 0; oo < 4; ++oo) {
                float wv = lw[(o0t + oo) * 129 + c0 + cl];
#pragma unroll
                for (int k = 0; k < 8; ++k) acc[oo][k] += wv * hv[k];
            }
        }
    }
    __syncthreads();
    ushort* lout = (ushort*)lhs;       // [t*64 + o]
#pragma unroll
    for (int oo = 0; oo < 4; ++oo)
#pragma unroll
        for (int k = 0; k < 8; ++k)
            lout[(t0 + k) * 64 + o0t + oo] = f2bf(acc[oo][k]);
    __syncthreads();
    for (int n = threadIdx.x; n < 8192; n += 256) {
        int t = n >> 6, o = n & 63;
        h2t[(size_t)(s * 128 + t) * 2048 + b * 512 + o0 + o] = lout[n];
    }
}

// ---------------------------------------------------------------------------
// E1: per mask column m=(s,i,j), collect nonzero (t,w) taps (<=6 exist, cap 8).
// ---------------------------------------------------------------------------
__global__ __launch_bounds__(256) void k_e1(
    const float* __restrict__ mask, uint32* __restrict__ ecnt,
    uint8_t* __restrict__ et, float* __restrict__ ew)
{
    uint32 m = blockIdx.x * 256 + threadIdx.x;
    int cnt = 0;
    for (int t = 0; t < 128; ++t) {
        float w = mask[(size_t)t * 524288 + m];
        if (w != 0.0f) {
            if (cnt < 8) {
                et[(size_t)m * 8 + cnt] = (uint8_t)t;
                ew[(size_t)m * 8 + cnt] = w;
            }
            cnt++;
        }
    }
    ecnt[m] = (uint32)(cnt < 8 ? cnt : 8);
}

// ---------------------------------------------------------------------------
// E2: merge per (i,j): taps over all 32 s -> packed {w_bits, byte_off} (<=192).
// byte_off = st * 4096 (h2t row pitch in bytes) so k_bm's inner loop is lean.
// ---------------------------------------------------------------------------
__global__ void k_e2(const uint32* __restrict__ ecnt, const uint8_t* __restrict__ et,
                     const float* __restrict__ ew, uint32* __restrict__ cntij,
                     int2* __restrict__ taps)
{
    int lane = threadIdx.x & 31;
    int col = blockIdx.x * 2 + (threadIdx.x >> 5);
    uint32 m = (uint32)lane * 16384u + (uint32)col;
    int c = (int)ecnt[m];
    int v = c;
    for (int d = 1; d < 32; d <<= 1) {
        int t = __shfl_up(v, d, 32);
        if (lane >= d) v += t;
    }
    int off = v - c;
    if (lane == 31) cntij[col] = (uint32)v;
    for (int k = 0; k < c; ++k) {
        int2 r;
        r.x = __float_as_int(ew[(size_t)m * 8 + k]);
        r.y = ((lane << 7) + (int)et[(size_t)m * 8 + k]) << 12;   // st * 4096 bytes
        taps[(size_t)col * 192 + off + k] = r;
    }
}

// ---------------------------------------------------------------------------
// k_bm: cm2[ij, bo] = relu(b3d[o] + sum_taps w * H2t[st, bo])   (bf16 out)
// Grid (x=boT 8, y = i*2 + jhalf): x fastest -> round-robin pins each bo-slice
// (2 MB of h2t) to one XCD's L2. 2048 blocks = 8 blocks/CU = 32 waves/CU for
// latency hiding. Direct coalesced nontemporal stores.
// ---------------------------------------------------------------------------
__global__ __launch_bounds__(256) void k_bm(
    const ushort* __restrict__ h2t, const int2* __restrict__ taps,
    const uint32* __restrict__ cntij, const float* __restrict__ b3d,
    ushort* __restrict__ cm2)
{
    __shared__ int2 tl[8 * 192];        // 12,288 B
    int boT = blockIdx.x;
    int i = blockIdx.y >> 1, jh = blockIdx.y & 1;
    int tid = threadIdx.x;
    int bo = boT * 256 + tid;
    uint32 bo_byte = (uint32)bo * 2u;
    float bias = b3d[bo & 511];
    const char* h2b = (const char*)h2t;

    for (int jc = 0; jc < 8; ++jc) {
        int j0 = jh * 64 + jc * 8;
        int ij0 = i * 128 + j0;
        int cnts[8];
#pragma unroll
        for (int c = 0; c < 8; ++c) cnts[c] = (int)cntij[ij0 + c];
        __syncthreads();   // previous chunk's readers done before tl overwrite
        for (int n = tid; n < 1536; n += 256) {
            int c = n / 192, k = n - c * 192;
            if (k < cnts[c]) tl[n] = taps[(size_t)(ij0 + c) * 192 + k];
        }
        __syncthreads();
#pragma unroll 1
        for (int c = 0; c < 8; ++c) {
            int cnt = cnts[c];
            const int2* tp = &tl[c * 192];
            float a = 0.0f;
#pragma unroll 16
            for (int k = 0; k < cnt; ++k) {
                int2 r = tp[k];
                ushort hv = *(const ushort*)(h2b + ((uint32)r.y + bo_byte));
                a += __int_as_float(r.x) * bf2f(hv);
            }
            float v = a + bias;
            v = v > 0.0f ? v : 0.0f;
            __builtin_nontemporal_store(f2bf(v), &cm2[(size_t)(ij0 + c) * 2048 + bo]);
        }
    }
}

// ---------------------------------------------------------------------------
// conv-a: 1x1, 512 -> 128, relu.  Reads cm2[ij][bo] layout.
// p1[b,c,ij] = relu(ba[c] + sum_o wa[c,o]*cm2[ij, b*512+o])
// ---------------------------------------------------------------------------
__global__ __launch_bounds__(256) void k_conva(
    const ushort* __restrict__ cm2, const float* __restrict__ wa,
    const float* __restrict__ ba, float* __restrict__ p1)
{
    __shared__ float lx[32 * 132];   // [oo][j]
    __shared__ float lwv[32 * 132];  // [oo][c]
    int i = blockIdx.x, b = blockIdx.y;
    int cg = threadIdx.x >> 4, jg = threadIdx.x & 15;
    int c0 = cg * 8, j0 = jg * 8;
    float acc[8][8];
#pragma unroll
    for (int cc = 0; cc < 8; ++cc)
#pragma unroll
        for (int k = 0; k < 8; ++k) acc[cc][k] = 0.0f;

    for (int o0 = 0; o0 < 512; o0 += 32) {
        __syncthreads();
        // stage 128 j x 32 o from cm2[(i*128+j)*2048 + b*512 + o0 + *]
        for (int n = threadIdx.x; n < 2048; n += 256) {
            int j = n >> 4, q = n & 15;            // q = o-pair index
            uint32 v = *(const uint32*)(cm2 + ((size_t)(i * 128 + j)) * 2048 + b * 512 + o0 + 2 * q);
            lx[(2 * q) * 132 + j]     = bf2f((ushort)(v & 0xffffu));
            lx[(2 * q + 1) * 132 + j] = bf2f((ushort)(v >> 16));
        }
        for (int n = threadIdx.x; n < 4096; n += 256) {
            int oo = n & 31, c = n >> 5;
            lwv[oo * 132 + c] = wa[(size_t)c * 512 + o0 + oo];
        }
        __syncthreads();
        for (int oo = 0; oo < 32; ++oo) {
            float xv[8], wvv[8];
#pragma unroll
            for (int k = 0; k < 8; ++k) xv[k] = lx[oo * 132 + j0 + k];
#pragma unroll
            for (int k = 0; k < 8; ++k) wvv[k] = lwv[oo * 132 + c0 + k];
#pragma unroll
            for (int cc = 0; cc < 8; ++cc)
#pragma unroll
                for (int k = 0; k < 8; ++k) acc[cc][k] += wvv[cc] * xv[k];
        }
    }
#pragma unroll
    for (int cc = 0; cc < 8; ++cc) {
        float bb = ba[c0 + cc];
#pragma unroll
        for (int k = 0; k < 8; ++k) {
            float v = acc[cc][k] + bb;
            v = v > 0.0f ? v : 0.0f;
            p1[((size_t)(b * 128 + c0 + cc)) * 16384 + i * 128 + j0 + k] = v;
        }
    }
}

// ---------------------------------------------------------------------------
// 3x3 conv, CIN -> 64, pad 1, relu. Stages 8 input channels per barrier.
// ---------------------------------------------------------------------------
template <int CIN>
__global__ __launch_bounds__(256) void k_conv3x3(
    const float* __restrict__ in, const float* __restrict__ w,
    const float* __restrict__ bias, float* __restrict__ out)
{
    __shared__ float lx[8][3 * 132];   // 8 ch x 3 rows, padded cols 0..129
    __shared__ float lws[8][576];      // 8 ch x (64 c_out x 9)
    int i = blockIdx.x, b = blockIdx.y;
    int cg = threadIdx.x >> 4, jg = threadIdx.x & 15;
    int c0 = cg * 4, j0 = jg * 8;
    float acc[4][8];
#pragma unroll
    for (int cc = 0; cc < 4; ++cc)
#pragma unroll
        for (int k = 0; k < 8; ++k) acc[cc][k] = 0.0f;

    for (int o0 = 0; o0 < CIN; o0 += 8) {
        __syncthreads();
        for (int n = threadIdx.x; n < 8 * 390; n += 256) {
            int ch = n / 390, m = n - ch * 390;
            int r = m / 130, col = m - r * 130;
            int ii = i + r - 1, jj = col - 1;
            float v = 0.0f;
            if (ii >= 0 && ii < 128 && jj >= 0 && jj < 128)
                v = in[((size_t)(b * CIN + o0 + ch) * 128 + ii) * 128 + jj];
            lx[ch][r * 132 + col] = v;
        }
        for (int n = threadIdx.x; n < 8 * 576; n += 256) {
            int ch = n / 576, m = n - ch * 576;
            lws[ch][m] = w[((size_t)(m / 9) * CIN + o0 + ch) * 9 + (m % 9)];
        }
        __syncthreads();

#pragma unroll 1
        for (int ch = 0; ch < 8; ++ch) {
            float x0[10], x1[10], x2[10];
#pragma unroll
            for (int k = 0; k < 10; ++k) {
                x0[k] = lx[ch][0 * 132 + j0 + k];
                x1[k] = lx[ch][1 * 132 + j0 + k];
                x2[k] = lx[ch][2 * 132 + j0 + k];
            }
#pragma unroll
            for (int cc = 0; cc < 4; ++cc) {
                const float* wp = &lws[ch][(c0 + cc) * 9];
                float w00 = wp[0], w01 = wp[1], w02 = wp[2];
                float w10 = wp[3], w11 = wp[4], w12 = wp[5];
                float w20 = wp[6], w21 = wp[7], w22 = wp[8];
#pragma unroll
                for (int k = 0; k < 8; ++k) {
                    acc[cc][k] += w00 * x0[k] + w01 * x0[k + 1] + w02 * x0[k + 2]
                                + w10 * x1[k] + w11 * x1[k + 1] + w12 * x1[k + 2]
                                + w20 * x2[k] + w21 * x2[k + 1] + w22 * x2[k + 2];
                }
            }
        }
    }
#pragma unroll
    for (int cc = 0; cc < 4; ++cc) {
        float bb = bias[c0 + cc];
#pragma unroll
        for (int k = 0; k < 8; ++k) {
            float v = acc[cc][k] + bb;
            v = v > 0.0f ? v : 0.0f;
            out[((size_t)(b * 64 + c0 + cc) * 128 + i) * 128 + j0 + k] = v;
        }
    }
}

// ---------------------------------------------------------------------------
// conv-d: 1x1, 64 -> 4, sigmoid, scatter to d_out floats
// ---------------------------------------------------------------------------
__global__ __launch_bounds__(256) void k_convd(
    const float* __restrict__ p3, const float* __restrict__ wd,
    const float* __restrict__ bd, float* __restrict__ outp)
{
    __shared__ float lw[256];
    int b = blockIdx.y;
    int ij = blockIdx.x * 256 + threadIdx.x;
    lw[threadIdx.x] = wd[threadIdx.x];
    __syncthreads();
    float a0 = bd[0], a1 = bd[1], a2 = bd[2], a3 = bd[3];
    for (int c = 0; c < 64; ++c) {
        float v = p3[((size_t)(b * 64 + c)) * 16384 + ij];
        a0 += lw[c] * v;
        a1 += lw[64 + c] * v;
        a2 += lw[128 + c] * v;
        a3 += lw[192 + c] * v;
    }
    outp[1536 + (size_t)(b * 2 + 0) * 16384 + ij] = sigmoidf(a2);  // iou ch0
    outp[1536 + (size_t)(b * 2 + 1) * 16384 + ij] = sigmoidf(a3);  // iou ch1
    outp[132608 + (size_t)b * 16384 + ij] = sigmoidf(a0);          // prop_start
    outp[198144 + (size_t)b * 16384 + ij] = sigmoidf(a1);          // prop_end
}

// ---------------------------------------------------------------------------
extern "C" void kernel_launch(void* const* d_in, const int* in_sizes, int n_in,
                              void* d_out, int out_size, void* d_ws, size_t ws_size,
                              hipStream_t stream)
{
    const float* x   = (const float*)d_in[0];
    const float* w1  = (const float*)d_in[1];
    const float* b1  = (const float*)d_in[2];
    const float* w2  = (const float*)d_in[3];
    const float* b2  = (const float*)d_in[4];
    const float* w3  = (const float*)d_in[5];
    const float* b3  = (const float*)d_in[6];
    const float* w3d = (const float*)d_in[7];
    const float* b3d = (const float*)d_in[8];
    const float* wa  = (const float*)d_in[9];
    const float* ba  = (const float*)d_in[10];
    const float* wb  = (const float*)d_in[11];
    const float* bb  = (const float*)d_in[12];
    const float* wc  = (const float*)d_in[13];
    const float* bc  = (const float*)d_in[14];
    const float* wd  = (const float*)d_in[15];
    const float* bd  = (const float*)d_in[16];
    const float* sm  = (const float*)d_in[17];
    float* outp = (float*)d_out;
    char* ws = (char*)d_ws;

    // workspace layout (with aliasing; peak ~127.3 MB)
    float*  h1    = (float*)(ws + 0);              //  1,048,576 B
    float*  h     = (float*)(ws + 1048576);        //    262,144 B
    ushort* h2t   = (ushort*)(ws + 1310720);       // 16,777,216 B
    uint32* ecnt  = (uint32*)(ws + 18087936);      //  2,097,152 B
    uint8_t* et   = (uint8_t*)(ws + 20185088);     //  4,194,304 B
    float*  ewf   = (float*)(ws + 24379392);       // 16,777,216 B
    uint32* cntij = (uint32*)(ws + 41156608);      //     65,536 B
    int2*   taps  = (int2*)(ws + 41222144);        // 25,165,824 B
    ushort* cm2   = (ushort*)(ws + 66387968);      // 67,108,864 B  [ij][bo]
    float*  p1    = (float*)(ws + 1310720);        // 33,554,432 B (aliases h2t+e-bufs; dead then)
    float*  p2    = (float*)(ws + 41222144);       // 16,777,216 B (aliases taps; dead then)
    float*  p3    = (float*)(ws + 66387968);       // 16,777,216 B (aliases cm2; dead then)

    dim3 blk(256);
    k_conv1d_relu<<<dim3(32, 4), blk, 0, stream>>>(x, w1, b1, h1, 200, 400, 512);
    k_conv1d_relu<<<dim3(8, 4), blk, 0, stream>>>(h1, w2, b2, h, 512, 512, 128);
    k_x4<<<1, 512, 0, stream>>>(h, w3, b3, outp);
    k_h2<<<dim3(8, 32, 4), blk, 0, stream>>>(h, w3d, h2t);
    k_e1<<<2048, blk, 0, stream>>>(sm, ecnt, et, ewf);
    k_e2<<<8192, 64, 0, stream>>>(ecnt, et, ewf, cntij, taps);
    k_bm<<<dim3(8, 256), blk, 0, stream>>>(h2t, taps, cntij, b3d, cm2);
    k_conva<<<dim3(128, 4), blk, 0, stream>>>(cm2, wa, ba, p1);
    k_conv3x3<128><<<dim3(128, 4), blk, 0, stream>>>(p1, wb, bb, p2);
    k_conv3x3<64><<<dim3(128, 4), blk, 0, stream>>>(p2, wc, bc, p3);
    k_convd<<<dim3(64, 4), blk, 0, stream>>>(p3, wd, bd, outp);
}

// Round 7
// 1142.113 us; speedup vs baseline: 1.7931x; 1.0579x over previous
//
#include <hip/hip_runtime.h>
#include <hip/hip_bf16.h>
#include <stdint.h>

// ---------------------------------------------------------------------------
// Problem geometry
//   x (4,400,128) -> conv1d(200->512,k3,p1,relu) -> conv1d(512->128,k3,p1,relu) = h
//   x4 = sigmoid(0.01*conv1d(h, w3(3,128,1))) -> outputs xc(ch2), xb_start(ch0), xb_end(ch1)
//   cm = einsum('bct,tm->bcm', h, mask) ; conv3d(w3d, stride 32) + b3d, relu
//     == relu(b3d[o] + sum_{s,t} mask[t,s,i,j] * H2[b,o,s,t]),
//        H2[b,o,s,t] = sum_c w3d[o,c,s] * h[b,c,t]      (mask: <=6 taps per (s,i,j))
//   then 1x1(512->128,relu), 3x3(128->64,relu), 3x3(64->64,relu), 1x1(64->4,sigmoid)
//   outputs (float32): xc,xb_start,xb_end (3*512) | iou (4,2,128,128) | prop_start | prop_end
//
// cm is stored TRANSPOSED: cm2[ij][bo] so k_bm stores coalesced directly.
// k_bm: thread owns a bo-PAIR (1 dword = 2 bf16 per tap load, 2 MACs);
// grid (x=boT 8 -> XCD-pinned 2MB h2t slice, y = i*4 + quarter).
// ---------------------------------------------------------------------------

typedef unsigned int uint32;

__device__ __forceinline__ float bf2f(ushort u) {
    return __uint_as_float(((uint32)u) << 16);
}
__device__ __forceinline__ ushort f2bf(float f) {
    uint32 x = __float_as_uint(f);
    uint32 r = (x + 0x7FFFu + ((x >> 16) & 1u)) >> 16;
    return (ushort)r;
}
__device__ __forceinline__ float sigmoidf(float x) {
    return 1.0f / (1.0f + __expf(-x));
}

// ---------------------------------------------------------------------------
// conv1d (k=3, pad=1, relu). Block: 16 out-channels x 128 t. Grid (COUT/16, B).
// ---------------------------------------------------------------------------
__global__ __launch_bounds__(256) void k_conv1d_relu(
    const float* __restrict__ in, const float* __restrict__ w,
    const float* __restrict__ bias, float* __restrict__ out,
    int CIN, int in_batch_stride, int COUT)
{
    __shared__ float lx[64 * 132];   // [c][0..127 data, 128 = zero pad]
    int b  = blockIdx.y;
    int o  = blockIdx.x * 16 + (threadIdx.x >> 4);
    int tg = threadIdx.x & 15;
    int t0 = tg * 8;

    float acc[8];
#pragma unroll
    for (int k = 0; k < 8; ++k) acc[k] = 0.0f;

    for (int c0 = 0; c0 < CIN; c0 += 64) {
        int nc = CIN - c0; if (nc > 64) nc = 64;
        __syncthreads();
        for (int n = threadIdx.x; n < nc * 32; n += 256) {
            int cl = n >> 5, q = n & 31;
            float4 v = *(const float4*)(in + ((size_t)(b * in_batch_stride + c0 + cl)) * 128 + q * 4);
            *(float4*)(&lx[cl * 132 + q * 4]) = v;
        }
        for (int cl = threadIdx.x; cl < nc; cl += 256) lx[cl * 132 + 128] = 0.0f;
        __syncthreads();

        for (int cl = 0; cl < nc; ++cl) {
            int c = c0 + cl;
            const float* wp = w + ((size_t)o * CIN + c) * 3;
            float w0 = wp[0], w1 = wp[1], w2 = wp[2];
            const float* row = &lx[cl * 132];
            float xv[10];
            if (t0 == 0) {
                xv[0] = 0.0f;
#pragma unroll
                for (int k = 1; k < 10; ++k) xv[k] = row[k - 1];
            } else {
#pragma unroll
                for (int k = 0; k < 10; ++k) xv[k] = row[t0 - 1 + k];
            }
#pragma unroll
            for (int k = 0; k < 8; ++k)
                acc[k] += w0 * xv[k] + w1 * xv[k + 1] + w2 * xv[k + 2];
        }
    }
    float bo = bias[o];
#pragma unroll
    for (int k = 0; k < 8; ++k) {
        float v = acc[k] + bo;
        out[((size_t)(b * COUT + o)) * 128 + t0 + k] = v > 0.0f ? v : 0.0f;
    }
}

// ---------------------------------------------------------------------------
// x4 head -> d_out[0:1536] floats: (xc=ch2 | xb_start=ch0 | xb_end=ch1)
// ---------------------------------------------------------------------------
__global__ void k_x4(const float* __restrict__ h, const float* __restrict__ w3,
                     const float* __restrict__ b3, float* __restrict__ outp)
{
    int tid = threadIdx.x;
    int b = tid >> 7, t = tid & 127;
    float a0 = 0.f, a1 = 0.f, a2 = 0.f;
    for (int c = 0; c < 128; ++c) {
        float hv = h[((size_t)(b * 128 + c)) * 128 + t];
        a0 += w3[c] * hv;
        a1 += w3[128 + c] * hv;
        a2 += w3[256 + c] * hv;
    }
    float s0 = sigmoidf(0.01f * (a0 + b3[0]));
    float s1 = sigmoidf(0.01f * (a1 + b3[1]));
    float s2 = sigmoidf(0.01f * (a2 + b3[2]));
    int bt = b * 128 + t;
    outp[bt]        = s2;   // xc
    outp[512 + bt]  = s0;   // xb_start
    outp[1024 + bt] = s1;   // xb_end
}

// ---------------------------------------------------------------------------
// H2t[(s*128+t)*2048 + b*512+o] = bf16( sum_c w3d[o,c,s]*h[b,c,t] )
// ---------------------------------------------------------------------------
__global__ __launch_bounds__(256) void k_h2(
    const float* __restrict__ h, const float* __restrict__ w3d,
    ushort* __restrict__ h2t)
{
    __shared__ float lw[64 * 129];     // [o][c]
    __shared__ float lhs[32 * 132];    // [c_local][t] ; reused as ushort out stage
    int ot = blockIdx.x, s = blockIdx.y, b = blockIdx.z;
    int o0 = ot * 64;

    for (int n = threadIdx.x; n < 8192; n += 256) {
        int o = n >> 7, c = n & 127;
        lw[o * 129 + c] = w3d[(size_t)(o0 + o) * 4096 + c * 32 + s];
    }

    int og = threadIdx.x >> 4, tg = threadIdx.x & 15;
    int o0t = og * 4, t0 = tg * 8;
    float acc[4][8];
#pragma unroll
    for (int oo = 0; oo < 4; ++oo)
#pragma unroll
        for (int k = 0; k < 8; ++k) acc[oo][k] = 0.0f;

    for (int c0 = 0; c0 < 128; c0 += 32) {
        __syncthreads();
        for (int n = threadIdx.x; n < 1024; n += 256) {
            int cl = n >> 5, q = n & 31;
            *(float4*)(&lhs[cl * 132 + q * 4]) =
                *(const float4*)(h + ((size_t)(b * 128 + c0 + cl)) * 128 + q * 4);
        }
        __syncthreads();
        for (int cl = 0; cl < 32; ++cl) {
            float hv[8];
#pragma unroll
            for (int k = 0; k < 8; ++k) hv[k] = lhs[cl * 132 + t0 + k];
#pragma unroll
            for (int oo = 0; oo < 4; ++oo) {
                float wv = lw[(o0t + oo) * 129 + c0 + cl];
#pragma unroll
                for (int k = 0; k < 8; ++k) acc[oo][k] += wv * hv[k];
            }
        }
    }
    __syncthreads();
    ushort* lout = (ushort*)lhs;       // [t*64 + o]
#pragma unroll
    for (int oo = 0; oo < 4; ++oo)
#pragma unroll
        for (int k = 0; k < 8; ++k)
            lout[(t0 + k) * 64 + o0t + oo] = f2bf(acc[oo][k]);
    __syncthreads();
    for (int n = threadIdx.x; n < 8192; n += 256) {
        int t = n >> 6, o = n & 63;
        h2t[(size_t)(s * 128 + t) * 2048 + b * 512 + o0 + o] = lout[n];
    }
}

// ---------------------------------------------------------------------------
// E1: per mask column m=(s,i,j), collect nonzero (t,w) taps (<=6 exist, cap 8).
// ---------------------------------------------------------------------------
__global__ __launch_bounds__(256) void k_e1(
    const float* __restrict__ mask, uint32* __restrict__ ecnt,
    uint8_t* __restrict__ et, float* __restrict__ ew)
{
    uint32 m = blockIdx.x * 256 + threadIdx.x;
    int cnt = 0;
    for (int t = 0; t < 128; ++t) {
        float w = mask[(size_t)t * 524288 + m];
        if (w != 0.0f) {
            if (cnt < 8) {
                et[(size_t)m * 8 + cnt] = (uint8_t)t;
                ew[(size_t)m * 8 + cnt] = w;
            }
            cnt++;
        }
    }
    ecnt[m] = (uint32)(cnt < 8 ? cnt : 8);
}

// ---------------------------------------------------------------------------
// E2: merge per (i,j): taps over all 32 s -> packed {w_bits, byte_off} (<=192).
// byte_off = st * 4096 (h2t row pitch in bytes) so k_bm's inner loop is lean.
// ---------------------------------------------------------------------------
__global__ void k_e2(const uint32* __restrict__ ecnt, const uint8_t* __restrict__ et,
                     const float* __restrict__ ew, uint32* __restrict__ cntij,
                     int2* __restrict__ taps)
{
    int lane = threadIdx.x & 31;
    int col = blockIdx.x * 2 + (threadIdx.x >> 5);
    uint32 m = (uint32)lane * 16384u + (uint32)col;
    int c = (int)ecnt[m];
    int v = c;
    for (int d = 1; d < 32; d <<= 1) {
        int t = __shfl_up(v, d, 32);
        if (lane >= d) v += t;
    }
    int off = v - c;
    if (lane == 31) cntij[col] = (uint32)v;
    for (int k = 0; k < c; ++k) {
        int2 r;
        r.x = __float_as_int(ew[(size_t)m * 8 + k]);
        r.y = ((lane << 7) + (int)et[(size_t)m * 8 + k]) << 12;   // st * 4096 bytes
        taps[(size_t)col * 192 + off + k] = r;
    }
}

// ---------------------------------------------------------------------------
// k_bm: cm2[ij, bo] = relu(b3d[o] + sum_taps w * H2t[st, bo])   (bf16 out)
// Thread owns bo-pair (2*tid, 2*tid+1): one dword load per tap = 2 bf16 = 2
// MACs, 2 independent FMA chains. Grid (x=boT 8, y = i*4 + quarter): x fastest
// pins each 2MB h2t bo-slice to one XCD's L2. 4096 blocks x 128 thr; LDS 12KB
// -> 13 blocks/CU (~26 waves). Empty columns (j<i) still store relu(bias).
// ---------------------------------------------------------------------------
__global__ __launch_bounds__(128) void k_bm(
    const ushort* __restrict__ h2t, const int2* __restrict__ taps,
    const uint32* __restrict__ cntij, const float* __restrict__ b3d,
    ushort* __restrict__ cm2)
{
    __shared__ int2 tl[8 * 192];        // 12,288 B
    int boT = blockIdx.x;
    int i = blockIdx.y >> 2, q = blockIdx.y & 3;
    int tid = threadIdx.x;
    int bo0 = boT * 256 + tid * 2;
    const char* hb = (const char*)h2t + (size_t)bo0 * 2;
    float bias0 = b3d[bo0 & 511];
    float bias1 = b3d[(bo0 & 511) + 1];
    uint32* cm32 = (uint32*)cm2;

    for (int jc = 0; jc < 4; ++jc) {
        int j0 = q * 32 + jc * 8;
        int ij0 = i * 128 + j0;
        int cnts[8];
#pragma unroll
        for (int c = 0; c < 8; ++c) cnts[c] = (int)cntij[ij0 + c];
        __syncthreads();   // previous chunk's readers done before tl overwrite
        for (int n = tid; n < 1536; n += 128) {
            int c = n / 192, k = n - c * 192;
            if (k < cnts[c]) tl[n] = taps[(size_t)(ij0 + c) * 192 + k];
        }
        __syncthreads();
#pragma unroll 1
        for (int c = 0; c < 8; ++c) {
            int cnt = cnts[c];
            const int2* tp = &tl[c * 192];
            float a0 = 0.0f, a1 = 0.0f;
#pragma unroll 16
            for (int k = 0; k < cnt; ++k) {
                int2 r = tp[k];
                uint32 hv = *(const uint32*)(hb + (uint32)r.y);
                float w = __int_as_float(r.x);
                a0 += w * __uint_as_float(hv << 16);
                a1 += w * __uint_as_float(hv & 0xffff0000u);
            }
            float v0 = a0 + bias0; v0 = v0 > 0.0f ? v0 : 0.0f;
            float v1 = a1 + bias1; v1 = v1 > 0.0f ? v1 : 0.0f;
            uint32 pr = (uint32)f2bf(v0) | ((uint32)f2bf(v1) << 16);
            __builtin_nontemporal_store(pr, &cm32[((size_t)(ij0 + c) * 2048 + bo0) >> 1]);
        }
    }
}

// ---------------------------------------------------------------------------
// conv-a: 1x1, 512 -> 128, relu.  Reads cm2[ij][bo] layout.
// p1[b,c,ij] = relu(ba[c] + sum_o wa[c,o]*cm2[ij, b*512+o])
// ---------------------------------------------------------------------------
__global__ __launch_bounds__(256) void k_conva(
    const ushort* __restrict__ cm2, const float* __restrict__ wa,
    const float* __restrict__ ba, float* __restrict__ p1)
{
    __shared__ float lx[32 * 132];   // [oo][j]
    __shared__ float lwv[32 * 132];  // [oo][c]
    int i = blockIdx.x, b = blockIdx.y;
    int cg = threadIdx.x >> 4, jg = threadIdx.x & 15;
    int c0 = cg * 8, j0 = jg * 8;
    float acc[8][8];
#pragma unroll
    for (int cc = 0; cc < 8; ++cc)
#pragma unroll
        for (int k = 0; k < 8; ++k) acc[cc][k] = 0.0f;

    for (int o0 = 0; o0 < 512; o0 += 32) {
        __syncthreads();
        // stage 128 j x 32 o from cm2[(i*128+j)*2048 + b*512 + o0 + *]
        for (int n = threadIdx.x; n < 2048; n += 256) {
            int j = n >> 4, q = n & 15;            // q = o-pair index
            uint32 v = *(const uint32*)(cm2 + ((size_t)(i * 128 + j)) * 2048 + b * 512 + o0 + 2 * q);
            lx[(2 * q) * 132 + j]     = bf2f((ushort)(v & 0xffffu));
            lx[(2 * q + 1) * 132 + j] = bf2f((ushort)(v >> 16));
        }
        for (int n = threadIdx.x; n < 4096; n += 256) {
            int oo = n & 31, c = n >> 5;
            lwv[oo * 132 + c] = wa[(size_t)c * 512 + o0 + oo];
        }
        __syncthreads();
        for (int oo = 0; oo < 32; ++oo) {
            float xv[8], wvv[8];
#pragma unroll
            for (int k = 0; k < 8; ++k) xv[k] = lx[oo * 132 + j0 + k];
#pragma unroll
            for (int k = 0; k < 8; ++k) wvv[k] = lwv[oo * 132 + c0 + k];
#pragma unroll
            for (int cc = 0; cc < 8; ++cc)
#pragma unroll
                for (int k = 0; k < 8; ++k) acc[cc][k] += wvv[cc] * xv[k];
        }
    }
#pragma unroll
    for (int cc = 0; cc < 8; ++cc) {
        float bb = ba[c0 + cc];
#pragma unroll
        for (int k = 0; k < 8; ++k) {
            float v = acc[cc][k] + bb;
            v = v > 0.0f ? v : 0.0f;
            p1[((size_t)(b * 128 + c0 + cc)) * 16384 + i * 128 + j0 + k] = v;
        }
    }
}

// ---------------------------------------------------------------------------
// 3x3 conv, CIN -> 64, pad 1, relu. Stages 8 input channels per barrier.
// ---------------------------------------------------------------------------
template <int CIN>
__global__ __launch_bounds__(256) void k_conv3x3(
    const float* __restrict__ in, const float* __restrict__ w,
    const float* __restrict__ bias, float* __restrict__ out)
{
    __shared__ float lx[8][3 * 132];   // 8 ch x 3 rows, padded cols 0..129
    __shared__ float lws[8][576];      // 8 ch x (64 c_out x 9)
    int i = blockIdx.x, b = blockIdx.y;
    int cg = threadIdx.x >> 4, jg = threadIdx.x & 15;
    int c0 = cg * 4, j0 = jg * 8;
    float acc[4][8];
#pragma unroll
    for (int cc = 0; cc < 4; ++cc)
#pragma unroll
        for (int k = 0; k < 8; ++k) acc[cc][k] = 0.0f;

    for (int o0 = 0; o0 < CIN; o0 += 8) {
        __syncthreads();
        for (int n = threadIdx.x; n < 8 * 390; n += 256) {
            int ch = n / 390, m = n - ch * 390;
            int r = m / 130, col = m - r * 130;
            int ii = i + r - 1, jj = col - 1;
            float v = 0.0f;
            if (ii >= 0 && ii < 128 && jj >= 0 && jj < 128)
                v = in[((size_t)(b * CIN + o0 + ch) * 128 + ii) * 128 + jj];
            lx[ch][r * 132 + col] = v;
        }
        for (int n = threadIdx.x; n < 8 * 576; n += 256) {
            int ch = n / 576, m = n - ch * 576;
            lws[ch][m] = w[((size_t)(m / 9) * CIN + o0 + ch) * 9 + (m % 9)];
        }
        __syncthreads();

#pragma unroll 1
        for (int ch = 0; ch < 8; ++ch) {
            float x0[10], x1[10], x2[10];
#pragma unroll
            for (int k = 0; k < 10; ++k) {
                x0[k] = lx[ch][0 * 132 + j0 + k];
                x1[k] = lx[ch][1 * 132 + j0 + k];
                x2[k] = lx[ch][2 * 132 + j0 + k];
            }
#pragma unroll
            for (int cc = 0; cc < 4; ++cc) {
                const float* wp = &lws[ch][(c0 + cc) * 9];
                float w00 = wp[0], w01 = wp[1], w02 = wp[2];
                float w10 = wp[3], w11 = wp[4], w12 = wp[5];
                float w20 = wp[6], w21 = wp[7], w22 = wp[8];
#pragma unroll
                for (int k = 0; k < 8; ++k) {
                    acc[cc][k] += w00 * x0[k] + w01 * x0[k + 1] + w02 * x0[k + 2]
                                + w10 * x1[k] + w11 * x1[k + 1] + w12 * x1[k + 2]
                                + w20 * x2[k] + w21 * x2[k + 1] + w22 * x2[k + 2];
                }
            }
        }
    }
#pragma unroll
    for (int cc = 0; cc < 4; ++cc) {
        float bb = bias[c0 + cc];
#pragma unroll
        for (int k = 0; k < 8; ++k) {
            float v = acc[cc][k] + bb;
            v = v > 0.0f ? v : 0.0f;
            out[((size_t)(b * 64 + c0 + cc) * 128 + i) * 128 + j0 + k] = v;
        }
    }
}

// ---------------------------------------------------------------------------
// conv-d: 1x1, 64 -> 4, sigmoid, scatter to d_out floats
// ---------------------------------------------------------------------------
__global__ __launch_bounds__(256) void k_convd(
    const float* __restrict__ p3, const float* __restrict__ wd,
    const float* __restrict__ bd, float* __restrict__ outp)
{
    __shared__ float lw[256];
    int b = blockIdx.y;
    int ij = blockIdx.x * 256 + threadIdx.x;
    lw[threadIdx.x] = wd[threadIdx.x];
    __syncthreads();
    float a0 = bd[0], a1 = bd[1], a2 = bd[2], a3 = bd[3];
    for (int c = 0; c < 64; ++c) {
        float v = p3[((size_t)(b * 64 + c)) * 16384 + ij];
        a0 += lw[c] * v;
        a1 += lw[64 + c] * v;
        a2 += lw[128 + c] * v;
        a3 += lw[192 + c] * v;
    }
    outp[1536 + (size_t)(b * 2 + 0) * 16384 + ij] = sigmoidf(a2);  // iou ch0
    outp[1536 + (size_t)(b * 2 + 1) * 16384 + ij] = sigmoidf(a3);  // iou ch1
    outp[132608 + (size_t)b * 16384 + ij] = sigmoidf(a0);          // prop_start
    outp[198144 + (size_t)b * 16384 + ij] = sigmoidf(a1);          // prop_end
}

// ---------------------------------------------------------------------------
extern "C" void kernel_launch(void* const* d_in, const int* in_sizes, int n_in,
                              void* d_out, int out_size, void* d_ws, size_t ws_size,
                              hipStream_t stream)
{
    const float* x   = (const float*)d_in[0];
    const float* w1  = (const float*)d_in[1];
    const float* b1  = (const float*)d_in[2];
    const float* w2  = (const float*)d_in[3];
    const float* b2  = (const float*)d_in[4];
    const float* w3  = (const float*)d_in[5];
    const float* b3  = (const float*)d_in[6];
    const float* w3d = (const float*)d_in[7];
    const float* b3d = (const float*)d_in[8];
    const float* wa  = (const float*)d_in[9];
    const float* ba  = (const float*)d_in[10];
    const float* wb  = (const float*)d_in[11];
    const float* bb  = (const float*)d_in[12];
    const float* wc  = (const float*)d_in[13];
    const float* bc  = (const float*)d_in[14];
    const float* wd  = (const float*)d_in[15];
    const float* bd  = (const float*)d_in[16];
    const float* sm  = (const float*)d_in[17];
    float* outp = (float*)d_out;
    char* ws = (char*)d_ws;

    // workspace layout (with aliasing; peak ~127.3 MB)
    float*  h1    = (float*)(ws + 0);              //  1,048,576 B
    float*  h     = (float*)(ws + 1048576);        //    262,144 B
    ushort* h2t   = (ushort*)(ws + 1310720);       // 16,777,216 B
    uint32* ecnt  = (uint32*)(ws + 18087936);      //  2,097,152 B
    uint8_t* et   = (uint8_t*)(ws + 20185088);     //  4,194,304 B
    float*  ewf   = (float*)(ws + 24379392);       // 16,777,216 B
    uint32* cntij = (uint32*)(ws + 41156608);      //     65,536 B
    int2*   taps  = (int2*)(ws + 41222144);        // 25,165,824 B
    ushort* cm2   = (ushort*)(ws + 66387968);      // 67,108,864 B  [ij][bo]
    float*  p1    = (float*)(ws + 1310720);        // 33,554,432 B (aliases h2t+e-bufs; dead then)
    float*  p2    = (float*)(ws + 41222144);       // 16,777,216 B (aliases taps; dead then)
    float*  p3    = (float*)(ws + 66387968);       // 16,777,216 B (aliases cm2; dead then)

    dim3 blk(256);
    k_conv1d_relu<<<dim3(32, 4), blk, 0, stream>>>(x, w1, b1, h1, 200, 400, 512);
    k_conv1d_relu<<<dim3(8, 4), blk, 0, stream>>>(h1, w2, b2, h, 512, 512, 128);
    k_x4<<<1, 512, 0, stream>>>(h, w3, b3, outp);
    k_h2<<<dim3(8, 32, 4), blk, 0, stream>>>(h, w3d, h2t);
    k_e1<<<2048, blk, 0, stream>>>(sm, ecnt, et, ewf);
    k_e2<<<8192, 64, 0, stream>>>(ecnt, et, ewf, cntij, taps);
    k_bm<<<dim3(8, 512), dim3(128), 0, stream>>>(h2t, taps, cntij, b3d, cm2);
    k_conva<<<dim3(128, 4), blk, 0, stream>>>(cm2, wa, ba, p1);
    k_conv3x3<128><<<dim3(128, 4), blk, 0, stream>>>(p1, wb, bb, p2);
    k_conv3x3<64><<<dim3(128, 4), blk, 0, stream>>>(p2, wc, bc, p3);
    k_convd<<<dim3(64, 4), blk, 0, stream>>>(p3, wd, bd, outp);
}